// Round 5
// baseline (218.982 us; speedup 1.0000x reference)
//
#include <hip/hip_runtime.h>
#include <hip/hip_bf16.h>
#include <math.h>

// Problem constants
#define NB    4
#define LQ    512
#define LKV   8192
#define QDIM  1024
#define KVDIM 512
#define NH    8
#define EPS_LN 1e-5f
#define SMAX  12.0f     // fixed softmax baseline (log2 domain); scores*log2e max ~9

typedef __attribute__((ext_vector_type(8))) short bf16x8;
typedef __attribute__((ext_vector_type(4))) float f32x4;

static __device__ __forceinline__ ushort f2bf(float x) {
    unsigned int u = __builtin_bit_cast(unsigned int, x);
    u += 0x7FFFu + ((u >> 16) & 1u);          // round-to-nearest-even
    return (ushort)(u >> 16);
}

#if __has_builtin(__builtin_amdgcn_cvt_pk_bf16_f32)
static __device__ __forceinline__ unsigned int pk_bf16(float a, float b) {
    auto r = __builtin_amdgcn_cvt_pk_bf16_f32(a, b);
    return __builtin_bit_cast(unsigned int, r);
}
#else
static __device__ __forceinline__ unsigned int pk_bf16(float a, float b) {
    return (unsigned int)f2bf(a) | ((unsigned int)f2bf(b) << 16);
}
#endif

#if __has_builtin(__builtin_amdgcn_exp2f)
#define EXP2F(x) __builtin_amdgcn_exp2f(x)
#else
#define EXP2F(x) exp2f(x)
#endif

// In-register 4-row interleave across 16-lane groups:
//   x in rows [a0,a1,a2,a3], y in rows [b0,b1,b2,b3]  (rows = 16-lane groups)
//   -> x = [a0,a2,b0,b2], y = [a1,a3,b1,b3]
// Used to convert the MFMA C/D row grouping (lg*4+r) into the K=32 B-operand
// grouping (lg*8+j) without touching LDS. permlane*_swap are full-rate VALU.
static __device__ __forceinline__ void interleave_swap(unsigned int &x, unsigned int &y, int lane) {
#if __has_builtin(__builtin_amdgcn_permlane32_swap) && __has_builtin(__builtin_amdgcn_permlane16_swap)
    {
        auto r1 = __builtin_amdgcn_permlane32_swap(x, y, false, false);
        auto r2 = __builtin_amdgcn_permlane16_swap(r1[0], r1[1], false, false);
        x = (unsigned int)r2[0];
        y = (unsigned int)r2[1];
    }
#else
    {
        // pl32swap: A2={x.r0,x.r1,y.r0,y.r1}, C2={x.r2,x.r3,y.r2,y.r3}
        unsigned int xs = (unsigned int)__shfl_xor((int)x, 32, 64);
        unsigned int ys = (unsigned int)__shfl_xor((int)y, 32, 64);
        unsigned int A2 = (lane & 32) ? ys : x;
        unsigned int C2 = (lane & 32) ? y  : xs;
        // pl16swap: x'={A2.r0,C2.r0,A2.r2,C2.r2}, y'={A2.r1,C2.r1,A2.r3,C2.r3}
        unsigned int A2x = (unsigned int)__shfl_xor((int)A2, 16, 64);
        unsigned int C2x = (unsigned int)__shfl_xor((int)C2, 16, 64);
        x = (lane & 16) ? C2x : A2;
        y = (lane & 16) ? C2  : A2x;
    }
#endif
}

// async global->LDS, 16B per lane; LDS dest = wave base + lane*16
static __device__ __forceinline__ void gld_lds16(const ushort* g, ushort* l) {
    __builtin_amdgcn_global_load_lds(
        (const __attribute__((address_space(1))) unsigned int*)g,
        (__attribute__((address_space(3))) unsigned int*)l, 16, 0, 0);
}

// ---------------------------------------------------------------------------
// LN normalize one row -> bf16 (wave per row).
// ---------------------------------------------------------------------------
template<int K>
static __device__ __forceinline__ void ln_norm_row(
    const float* __restrict__ x, const float* __restrict__ g,
    const float* __restrict__ bta, ushort* __restrict__ y, int row, int lane)
{
    const float* xp = x + (size_t)row * K;
    constexpr int NV = K / 256;
    float4 v[NV];
    float s = 0.f;
#pragma unroll
    for (int i = 0; i < NV; ++i) {
        v[i] = *(const float4*)(xp + lane * 4 + i * 256);
        s += v[i].x + v[i].y + v[i].z + v[i].w;
    }
#pragma unroll
    for (int o = 1; o < 64; o <<= 1) s += __shfl_xor(s, o, 64);
    const float mu = s * (1.0f / K);
    float vs = 0.f;
#pragma unroll
    for (int i = 0; i < NV; ++i) {
        float dx = v[i].x - mu, dy = v[i].y - mu, dz = v[i].z - mu, dw = v[i].w - mu;
        vs += dx * dx + dy * dy + dz * dz + dw * dw;
    }
#pragma unroll
    for (int o = 1; o < 64; o <<= 1) vs += __shfl_xor(vs, o, 64);
    const float rs = rsqrtf(vs * (1.0f / K) + EPS_LN);
#pragma unroll
    for (int i = 0; i < NV; ++i) {
        const float4 gv = *(const float4*)(g   + lane * 4 + i * 256);
        const float4 bv = *(const float4*)(bta + lane * 4 + i * 256);
        uint2 o;
        o.x = pk_bf16((v[i].x - mu) * rs * gv.x + bv.x, (v[i].y - mu) * rs * gv.y + bv.y);
        o.y = pk_bf16((v[i].z - mu) * rs * gv.z + bv.z, (v[i].w - mu) * rs * gv.w + bv.w);
        *(uint2*)(y + (size_t)row * K + lane * 4 + i * 256) = o;
    }
}

// LN stats only (K=1024), wave per row.
static __device__ __forceinline__ void ln_stats_row(
    const float* __restrict__ x, float* __restrict__ mean, float* __restrict__ rstd,
    int row, int lane)
{
    const float* xp = x + (size_t)row * QDIM;
    float4 v[4];
    float s = 0.f;
#pragma unroll
    for (int i = 0; i < 4; ++i) {
        v[i] = *(const float4*)(xp + lane * 4 + i * 256);
        s += v[i].x + v[i].y + v[i].z + v[i].w;
    }
#pragma unroll
    for (int o = 1; o < 64; o <<= 1) s += __shfl_xor(s, o, 64);
    const float mu = s * (1.0f / QDIM);
    float vs = 0.f;
#pragma unroll
    for (int i = 0; i < 4; ++i) {
        float dx = v[i].x - mu, dy = v[i].y - mu, dz = v[i].z - mu, dw = v[i].w - mu;
        vs += dx * dx + dy * dy + dz * dz + dw * dw;
    }
#pragma unroll
    for (int o = 1; o < 64; o <<= 1) vs += __shfl_xor(vs, o, 64);
    if (lane == 0) {
        mean[row] = mu;
        rstd[row] = rsqrtf(vs * (1.0f / QDIM) + EPS_LN);
    }
}

// 64x64 transpose tile: dst[n][k] = bf16(src[k][n]), src is [K][256].
static __device__ __forceinline__ void wt_transpose_body(
    const float* __restrict__ src, ushort* __restrict__ dst, int K,
    int kx, int ny, int t, ushort (*Ts)[72])
{
    const int k0 = kx * 64, n0 = ny * 64;
    const int nl = t & 63;
#pragma unroll
    for (int p = 0; p < 16; ++p) {
        const int kl = p * 4 + (t >> 6);
        Ts[nl][kl] = f2bf(src[(size_t)(k0 + kl) * 256 + n0 + nl]);
    }
    __syncthreads();
    const int ck = (t & 7) * 8;
#pragma unroll
    for (int p = 0; p < 2; ++p) {
        const int rn = p * 32 + (t >> 3);
        *(bf16x8*)(dst + (size_t)(n0 + rn) * K + k0 + ck) = *(const bf16x8*)&Ts[rn][ck];
    }
}

// ---------------------------------------------------------------------------
// Phase A (one launch): KV normalize (8192 blk) + Q LN stats (512 blk)
// + Wq/Wk/Wv transposes (64+32+32 blk). 256 threads.
// ---------------------------------------------------------------------------
__global__ __launch_bounds__(256) void phaseA_kernel(
    const float* __restrict__ inputs, const float* __restrict__ ln2g,
    const float* __restrict__ ln2b,   ushort* __restrict__ Abf,
    const float* __restrict__ hidden, float* __restrict__ mean_h, float* __restrict__ rstd_h,
    const float* __restrict__ Wq, const float* __restrict__ Wk, const float* __restrict__ Wv,
    ushort* __restrict__ WtQ, ushort* __restrict__ WtKV)
{
    __shared__ ushort Ts[64][72];
    const int bid = blockIdx.x;
    const int t = threadIdx.x;
    const int lane = t & 63;
    if (bid < 8192) {
        ln_norm_row<KVDIM>(inputs, ln2g, ln2b, Abf, bid * 4 + (t >> 6), lane);
    } else if (bid < 8704) {
        ln_stats_row(hidden, mean_h, rstd_h, (bid - 8192) * 4 + (t >> 6), lane);
    } else if (bid < 8768) {
        const int p = bid - 8704;
        wt_transpose_body(Wq, WtQ, QDIM, p & 15, p >> 4, t, Ts);
    } else if (bid < 8800) {
        const int p = bid - 8768;
        wt_transpose_body(Wk, WtKV, KVDIM, p & 7, p >> 3, t, Ts);
    } else {
        const int p = bid - 8800;
        wt_transpose_body(Wv, WtKV + (size_t)256 * KVDIM, KVDIM, p & 7, p >> 3, t, Ts);
    }
}

// ---------------------------------------------------------------------------
// Phase B (one launch, 256 thr): blocks [0,1024) = KV GEMM (128x128, BK=32),
// blocks [1024,1152) = Q GEMM (64x64, BK=64, LN fused into A staging).
// Both K and V epilogues go through per-wave LDS transpose -> 16B stores.
// ---------------------------------------------------------------------------
__global__ __launch_bounds__(256) void phaseB_kernel(
    const ushort* __restrict__ Abf, const ushort* __restrict__ WtKV,
    const float* __restrict__ bk, const float* __restrict__ bv,
    ushort* __restrict__ kb, ushort* __restrict__ vt,
    const float* __restrict__ hidden, const float* __restrict__ mean_h,
    const float* __restrict__ rstd_h,
    const float* __restrict__ ln1g, const float* __restrict__ ln1b,
    const ushort* __restrict__ WtQ, const float* __restrict__ bq,
    ushort* __restrict__ qb, float oscale)
{
    __shared__ __align__(16) ushort SMEM[4 * 64 * 72];   // 36864 B
    const int bid  = blockIdx.x;
    const int t    = threadIdx.x;
    const int lane = t & 63;
    const int w    = t >> 6;
    const int lq   = lane & 15;
    const int lg   = lane >> 4;
    const int wm   = w >> 1;
    const int wn   = w & 1;

    if (bid < 1024) {
        // ================= KV GEMM =================
        const int bm = (bid >> 2) * 128;
        const int bn = (bid & 3) * 128;
        ushort* As = SMEM;
        ushort* Bs = SMEM + 4096;

        const int srow = t >> 2;                              // 0..63
        const int scol = ((t & 3) ^ ((t >> 3) & 3)) * 8;      // xor-swizzled col
        const ushort* gA = Abf  + (size_t)(bm + srow) * KVDIM + scol;
        const ushort* gB = WtKV + (size_t)(bn + srow) * KVDIM + scol;
        ushort* lA = As + t * 8;
        ushort* lB = Bs + t * 8;

        f32x4 acc[4][4] = {};
        for (int k0 = 0; k0 < KVDIM; k0 += 32) {
            gld_lds16(gA + k0,                       lA);
            gld_lds16(gA + (size_t)64 * KVDIM + k0,  lA + 2048);
            gld_lds16(gB + k0,                       lB);
            gld_lds16(gB + (size_t)64 * KVDIM + k0,  lB + 2048);
            __syncthreads();
            bf16x8 af[4], bf[4];
#pragma unroll
            for (int mt = 0; mt < 4; ++mt) {
                const int m = wm * 64 + mt * 16 + lq;
                af[mt] = *(const bf16x8*)(As + m * 32 + ((lg ^ ((m >> 1) & 3)) << 3));
            }
#pragma unroll
            for (int nt = 0; nt < 4; ++nt) {
                const int n = wn * 64 + nt * 16 + lq;
                bf[nt] = *(const bf16x8*)(Bs + n * 32 + ((lg ^ ((n >> 1) & 3)) << 3));
            }
#pragma unroll
            for (int mt = 0; mt < 4; ++mt)
#pragma unroll
                for (int nt = 0; nt < 4; ++nt)
                    acc[mt][nt] = __builtin_amdgcn_mfma_f32_16x16x32_bf16(af[mt], bf[nt], acc[mt][nt], 0, 0, 0);
            __syncthreads();
        }
        // After the final barrier all As/Bs reads are done; per-wave Cs regions
        // (which overlap As/Bs for waves 0,1) are safe — per-wave use only.
        const int m0base = bm + wm * 64;
        const int bidx   = m0base >> 13;
        const int tokb   = m0base & 8191;

        if (bn < 256) {
            // ---- K path: LDS transpose Cs[tok_l][n_l] -> 16B row stores ----
            ushort (*Cs)[72] = (ushort(*)[72])(SMEM + w * 64 * 72);
#pragma unroll
            for (int nt = 0; nt < 4; ++nt) {
                const int n_l = nt * 16 + lq;
                const float bias = bk[bn + wn * 64 + n_l];
#pragma unroll
                for (int mt = 0; mt < 4; ++mt)
#pragma unroll
                    for (int r = 0; r < 4; ++r)
                        Cs[mt * 16 + lg * 4 + r][n_l] = f2bf(acc[mt][nt][r] + bias);
            }
            const int r0 = lane >> 3;
            const int ck = (lane & 7) * 8;
            const int nc = bn + wn * 64 + ck;
            const int h = nc >> 5, d = nc & 31;
            const size_t obase = (((size_t)(bidx * NH + h) << 13) + tokb) * 32 + d;
#pragma unroll
            for (int p = 0; p < 8; ++p) {
                const int row = p * 8 + r0;
                *(bf16x8*)(kb + obase + (size_t)row * 32) = *(const bf16x8*)&Cs[row][ck];
            }
        } else {
            // ---- V path: vT[bh][d][tok] via per-wave LDS transpose ----
            ushort (*Cs)[72] = (ushort(*)[72])(SMEM + w * 64 * 72);
#pragma unroll
            for (int nt = 0; nt < 4; ++nt) {
                const int n_l = nt * 16 + lq;
                const float bias = bv[(bn - 256) + wn * 64 + n_l];
#pragma unroll
                for (int mt = 0; mt < 4; ++mt) {
                    uint2 o;
                    o.x = pk_bf16(acc[mt][nt][0] + bias, acc[mt][nt][1] + bias);
                    o.y = pk_bf16(acc[mt][nt][2] + bias, acc[mt][nt][3] + bias);
                    *(uint2*)&Cs[n_l][mt * 16 + lg * 4] = o;
                }
            }
            const int r0 = lane >> 3;
            const int cm = (lane & 7) * 8;
            const int tokc = tokb + cm;
#pragma unroll
            for (int p = 0; p < 8; ++p) {
                const int row = p * 8 + r0;
                const int nv  = (bn - 256) + wn * 64 + row;
                const int h = nv >> 5, d = nv & 31;
                *(bf16x8*)(vt + ((size_t)(bidx * NH + h) * 32 + d) * LKV + tokc) =
                    *(const bf16x8*)&Cs[row][cm];
            }
        }
    } else {
        // ================= Q GEMM (LN fused) =================
        const int p  = bid - 1024;
        const int bm = (p >> 2) * 64;
        const int bn = (p & 3) * 64;
        ushort* As = SMEM;
        ushort* Bs = SMEM + 4096;

        const int srow = t >> 3;                              // 0..31
        const int scol = ((t & 7) ^ (srow & 7)) * 8;          // xor-swizzled col
        const ushort* gB = WtQ + (size_t)(bn + srow) * QDIM + scol;
        ushort* lB  = Bs + t * 8;
        ushort* lA0 = As + t * 8;
        ushort* lA1 = As + 2048 + t * 8;

        const int r0 = bm + srow;
        const float mu0 = mean_h[r0],      rs0 = rstd_h[r0];
        const float mu1 = mean_h[r0 + 32], rs1 = rstd_h[r0 + 32];
        const float* xA0 = hidden + (size_t)r0 * QDIM + scol;
        const float* xA1 = xA0 + (size_t)32 * QDIM;

        f32x4 acc[2][2] = {};
        for (int k0 = 0; k0 < QDIM; k0 += 64) {
            gld_lds16(gB + k0,                      lB);
            gld_lds16(gB + (size_t)32 * QDIM + k0,  lB + 2048);
            const float4 a0 = *(const float4*)(xA0 + k0);
            const float4 a1 = *(const float4*)(xA0 + k0 + 4);
            const float4 c0 = *(const float4*)(xA1 + k0);
            const float4 c1 = *(const float4*)(xA1 + k0 + 4);
            const float4 g0 = *(const float4*)(ln1g + k0 + scol);
            const float4 g1 = *(const float4*)(ln1g + k0 + scol + 4);
            const float4 d0 = *(const float4*)(ln1b + k0 + scol);
            const float4 d1 = *(const float4*)(ln1b + k0 + scol + 4);
            uint4 w0, w1;
            w0.x = pk_bf16((a0.x - mu0) * rs0 * g0.x + d0.x, (a0.y - mu0) * rs0 * g0.y + d0.y);
            w0.y = pk_bf16((a0.z - mu0) * rs0 * g0.z + d0.z, (a0.w - mu0) * rs0 * g0.w + d0.w);
            w0.z = pk_bf16((a1.x - mu0) * rs0 * g1.x + d1.x, (a1.y - mu0) * rs0 * g1.y + d1.y);
            w0.w = pk_bf16((a1.z - mu0) * rs0 * g1.z + d1.z, (a1.w - mu0) * rs0 * g1.w + d1.w);
            w1.x = pk_bf16((c0.x - mu1) * rs1 * g0.x + d0.x, (c0.y - mu1) * rs1 * g0.y + d0.y);
            w1.y = pk_bf16((c0.z - mu1) * rs1 * g0.z + d0.z, (c0.w - mu1) * rs1 * g0.w + d0.w);
            w1.z = pk_bf16((c1.x - mu1) * rs1 * g1.x + d1.x, (c1.y - mu1) * rs1 * g1.y + d1.y);
            w1.w = pk_bf16((c1.z - mu1) * rs1 * g1.z + d1.z, (c1.w - mu1) * rs1 * g1.w + d1.w);
            *(uint4*)lA0 = w0;
            *(uint4*)lA1 = w1;
            __syncthreads();
#pragma unroll
            for (int kh = 0; kh < 2; ++kh) {
                bf16x8 af[2], bf[2];
#pragma unroll
                for (int mt = 0; mt < 2; ++mt) {
                    const int m = wm * 32 + mt * 16 + lq;
                    af[mt] = *(const bf16x8*)(As + m * 64 + (((lg + 4 * kh) ^ (m & 7)) << 3));
                }
#pragma unroll
                for (int nt = 0; nt < 2; ++nt) {
                    const int n = wn * 32 + nt * 16 + lq;
                    bf[nt] = *(const bf16x8*)(Bs + n * 64 + (((lg + 4 * kh) ^ (n & 7)) << 3));
                }
#pragma unroll
                for (int mt = 0; mt < 2; ++mt)
#pragma unroll
                    for (int nt = 0; nt < 2; ++nt)
                        acc[mt][nt] = __builtin_amdgcn_mfma_f32_16x16x32_bf16(af[mt], bf[nt], acc[mt][nt], 0, 0, 0);
            }
            __syncthreads();
        }

#pragma unroll
        for (int nt = 0; nt < 2; ++nt) {
            const int n = bn + wn * 32 + nt * 16 + lq;
            const int h = n >> 5, d = n & 31;
            const float bias = bq[n];
#pragma unroll
            for (int mt = 0; mt < 2; ++mt) {
                const int m0   = bm + wm * 32 + mt * 16 + lg * 4;
                const int bidx = m0 >> 9;
                const int tok  = m0 & 511;
                const size_t base = (((size_t)(bidx * NH + h) << 9) + tok) * 32 + d;
#pragma unroll
                for (int r = 0; r < 4; ++r)
                    qb[base + (size_t)r * 32] = f2bf((acc[mt][nt][r] + bias) * oscale);
            }
        }
    }
}

// ---------------------------------------------------------------------------
// MFMA flash attention, fixed-baseline softmax, q-tile 32, 64-KV iterations.
// Inner loop identical to the proven 52.5us version. Packing lever: blocks are
// now 256 thr = 4 waves = ONE wave per SIMD, so per-CU residency is limited by
// the true per-wave register footprint (~100 incl. AGPRs -> 5 waves/SIMD =
// 20 waves/CU) instead of the 8-wave block quantum (which capped at 2 blocks =
// 16 waves/CU). Grid 2048 = 4 KV-quarters x 16 qt x 32 bh (XCD-swizzled).
// Wave w owns KV [quarter*2048 + w*512, +512) = 8 iterations. Partials
// (unnormalized O 32x32 f32 + l) per quarter; attn_combine merges 4.
// ---------------------------------------------------------------------------
__global__ __launch_bounds__(256, 4) void attn_mfma_kernel(
    const ushort* __restrict__ Qb,  // [B*H][LQ][32] bf16, pre-scaled by log2e/sqrt(32)
    const ushort* __restrict__ Kb,  // [B*H][LKV][32]
    const ushort* __restrict__ Vt,  // [B*H][32][LKV]
    float* __restrict__ Opart,      // [4][32][16][32q][32d] f32 partials
    float* __restrict__ lpart)      // [4][32][16][32q] f32 partials
{
    const int bid = blockIdx.x;
    const int xcd = bid & 7;
    const int rr  = bid >> 3;                // 0..255
    const int bh  = ((rr & 3) << 3) | xcd;   // 4 bh per XCD -> K/V L2-resident
    const int qt  = (rr >> 2) & 15;          // 0..15 (q-tile of 32)
    const int quarter = rr >> 6;             // 0..3: KV quarter [q*2048, +2048)
    const int t = threadIdx.x, w = t >> 6, lane = t & 63;
    const int lq = lane & 15, lg = lane >> 4;

    __shared__ __align__(16) float Ob[2 * 32 * 36];   // 9216 B combine scratch
    __shared__ float lbuf[4][32];

    // Q frags (B operand of QK): lane holds Q[q=n*16+lq][k=lg*8+j]
    bf16x8 qfrag[2];
    const size_t qbase = ((size_t)bh * LQ + qt * 32) * 32;
    qfrag[0] = *(const bf16x8*)(Qb + qbase + (size_t)lq * 32 + lg * 8);
    qfrag[1] = *(const bf16x8*)(Qb + qbase + (size_t)(16 + lq) * 32 + lg * 8);

    const int kv0 = quarter * 2048 + w * 512;
    const ushort* KpA = Kb + ((size_t)bh * LKV + kv0 + lq) * 32 + lg * 8;
    const ushort* VpA = Vt + ((size_t)bh * 32 + lq) * LKV + kv0 + lg * 8;

    f32x4 oacc[2][2] = {};        // [d-tile][q-tile]
    float l_part[2] = {0.f, 0.f};
    const f32x4 cM = {-SMAX, -SMAX, -SMAX, -SMAX};

    // prologue: K frags for iter 0 (A operand of QK: lane = K[kv=lq][k=lg*8+j])
    bf16x8 kf[4];
#pragma unroll
    for (int m = 0; m < 4; ++m)
        kf[m] = *(const bf16x8*)(KpA + (size_t)(m * 16) * 32);

    for (int kt = 0; kt < 512; kt += 64) {
        bf16x8 kc[4];
#pragma unroll
        for (int m = 0; m < 4; ++m) kc[m] = kf[m];

        // V frags for THIS iter (A operand of PV): V^T[d=dt*16+lq][kv=kt+hf*32+lg*8+j]
        // issued here, consumed after QK+softmax (~250 cyc) -> L2 latency hidden
        bf16x8 vc[2][2];
#pragma unroll
        for (int dt = 0; dt < 2; ++dt)
#pragma unroll
            for (int hf = 0; hf < 2; ++hf)
                vc[dt][hf] = *(const bf16x8*)(VpA + (size_t)(dt * 16) * LKV + kt + hf * 32);

        // prefetch K frags for NEXT iter (clamp: harmless re-read of kt=0)
        const int nk = (kt + 64 < 512) ? kt + 64 : 0;
#pragma unroll
        for (int m = 0; m < 4; ++m)
            kf[m] = *(const bf16x8*)(KpA + (size_t)(nk + m * 16) * 32);

        // S^T[kv64][q32] = K.Q^T - SMAX   (lane: kv=m*16+lg*4+r, q=n*16+lq)
        f32x4 s[4][2];
#pragma unroll
        for (int m = 0; m < 4; ++m)
#pragma unroll
            for (int n = 0; n < 2; ++n)
                s[m][n] = __builtin_amdgcn_mfma_f32_16x16x32_bf16(kc[m], qfrag[n], cM, 0, 0, 0);

        // exp2 + pack + permlane interleave -> PV B-frags, all in-register.
        // Per (n, kv32-block z): rows-of-pairs A=[p0,p2,p4,p6], B=[p1,p3,p5,p7],
        // C=[p8,p10,p12,p14], D=[p9,p11,p13,p15]; interleave_swap(A,C)->W0,W2;
        // (B,D)->W1,W3; [W0,W1,W2,W3] == B-operand words (kv pair 4*lg+w).
        bf16x8 pf[2][2];
#pragma unroll
        for (int n = 0; n < 2; ++n) {
#pragma unroll
            for (int z = 0; z < 2; ++z) {
                const float e0 = EXP2F(s[2 * z][n][0]);
                const float e1 = EXP2F(s[2 * z][n][1]);
                const float e2 = EXP2F(s[2 * z][n][2]);
                const float e3 = EXP2F(s[2 * z][n][3]);
                const float f0 = EXP2F(s[2 * z + 1][n][0]);
                const float f1 = EXP2F(s[2 * z + 1][n][1]);
                const float f2 = EXP2F(s[2 * z + 1][n][2]);
                const float f3 = EXP2F(s[2 * z + 1][n][3]);
                l_part[n] += ((e0 + e1) + (e2 + e3)) + ((f0 + f1) + (f2 + f3));
                unsigned int wa = pk_bf16(e0, e1);
                unsigned int wb = pk_bf16(e2, e3);
                unsigned int wc = pk_bf16(f0, f1);
                unsigned int wd = pk_bf16(f2, f3);
                interleave_swap(wa, wc, lane);   // wa=W0, wc=W2
                interleave_swap(wb, wd, lane);   // wb=W1, wd=W3
                uint4 wv;
                wv.x = wa; wv.y = wb; wv.z = wc; wv.w = wd;
                pf[n][z] = __builtin_bit_cast(bf16x8, wv);
            }
        }

        // O^T[d32][q32] += V^T . P^T
#pragma unroll
        for (int dt = 0; dt < 2; ++dt)
#pragma unroll
            for (int n = 0; n < 2; ++n) {
                oacc[dt][n] = __builtin_amdgcn_mfma_f32_16x16x32_bf16(vc[dt][0], pf[n][0], oacc[dt][n], 0, 0, 0);
                oacc[dt][n] = __builtin_amdgcn_mfma_f32_16x16x32_bf16(vc[dt][1], pf[n][1], oacc[dt][n], 0, 0, 0);
            }
    }

    // ---- l reduce + 4-wave combine -> partial write ----
#pragma unroll
    for (int n = 0; n < 2; ++n) {
        l_part[n] += __shfl_xor(l_part[n], 16);
        l_part[n] += __shfl_xor(l_part[n], 32);
    }
    if (lg == 0) {
        lbuf[w][lq]      = l_part[0];
        lbuf[w][16 + lq] = l_part[1];
    }
    if (w >= 2) {
#pragma unroll
        for (int n = 0; n < 2; ++n)
#pragma unroll
            for (int dt = 0; dt < 2; ++dt)
                *(f32x4*)&Ob[((size_t)(w - 2) * 32 + n * 16 + lq) * 36 + dt * 16 + lg * 4] = oacc[dt][n];
    }
    __syncthreads();
    if (w < 2) {
#pragma unroll
        for (int n = 0; n < 2; ++n)
#pragma unroll
            for (int dt = 0; dt < 2; ++dt) {
                float* p = &Ob[((size_t)w * 32 + n * 16 + lq) * 36 + dt * 16 + lg * 4];
                f32x4 v = *(f32x4*)p;
                v += oacc[dt][n];
                *(f32x4*)p = v;
            }
    }
    __syncthreads();
    {
        const int pidx = (quarter * 32 + bh) * 16 + qt;
        const int q  = t >> 3;           // 0..31
        const int d0 = (t & 7) * 4;      // 0..28
        f32x4 s0 = *(const f32x4*)&Ob[((size_t)q) * 36 + d0];
        f32x4 s1 = *(const f32x4*)&Ob[((size_t)(32 + q)) * 36 + d0];
        s0 += s1;
        *(f32x4*)(Opart + (size_t)pidx * 1024 + q * 32 + d0) = s0;
        if ((t & 7) == 0) {
            float gl = lbuf[0][q] + lbuf[1][q] + lbuf[2][q] + lbuf[3][q];
            lpart[(size_t)pidx * 32 + q] = gl;
        }
    }
}

// ---------------------------------------------------------------------------
// Combine the 4 KV-quarter partials: Out = sum(Oq)/sum(lq). Grid 512 =
// bh*16+qt, 256 thr, float4 per thread.
// ---------------------------------------------------------------------------
__global__ __launch_bounds__(256) void attn_combine_kernel(
    const float* __restrict__ Opart, const float* __restrict__ lpart,
    float* __restrict__ Out)
{
    const int cb = blockIdx.x;               // 0..511
    const int bh = cb >> 4, qt = cb & 15;
    const int b = bh >> 3, h = bh & 7;
    const int t = threadIdx.x;
    const int q = t >> 3;                    // 0..31
    const int dq = (t & 7) * 4;              // 0..28
    float4 o = {0.f, 0.f, 0.f, 0.f};
    float l = 0.f;
#pragma unroll
    for (int j = 0; j < 4; ++j) {
        const size_t pidx = (size_t)((j * 32 + bh) * 16 + qt);
        const float4 a = *(const float4*)(Opart + pidx * 1024 + q * 32 + dq);
        o.x += a.x; o.y += a.y; o.z += a.z; o.w += a.w;
        l += lpart[pidx * 32 + q];
    }
    const float inv = 1.0f / l;
    o.x *= inv; o.y *= inv; o.z *= inv; o.w *= inv;
    *(float4*)(Out + ((size_t)b * LQ + qt * 32 + q) * 256 + h * 32 + dq) = o;
}

// ---------------------------------------------------------------------------
extern "C" void kernel_launch(void* const* d_in, const int* in_sizes, int n_in,
                              void* d_out, int out_size, void* d_ws, size_t ws_size,
                              hipStream_t stream)
{
    const float* hidden = (const float*)d_in[0];
    const float* inputs = (const float*)d_in[1];
    const float* ln1g   = (const float*)d_in[2];
    const float* ln1b   = (const float*)d_in[3];
    const float* ln2g   = (const float*)d_in[4];
    const float* ln2b   = (const float*)d_in[5];
    const float* Wq     = (const float*)d_in[6];
    const float* bq     = (const float*)d_in[7];
    const float* Wk     = (const float*)d_in[8];
    const float* bk     = (const float*)d_in[9];
    const float* Wv     = (const float*)d_in[10];
    const float* bv     = (const float*)d_in[11];
    float* out = (float*)d_out;

    // workspace (bytes), total ~66 MB
    char* wsb = (char*)d_ws;
    ushort* qb     = (ushort*)(wsb);                               // 1 MB   [32][512][32]
    ushort* WtKV   = (ushort*)(wsb + (1u << 20));                  // 0.5 MB [512][512]
    ushort* WtQ    = (ushort*)(wsb + (1u << 20) + (512u << 10));   // 0.5 MB [256][1024]
    float*  mean_h = (float*)(wsb + (2u << 20));                   // 8 KB
    float*  rstd_h = (float*)(wsb + (2u << 20) + 8192);            // 8 KB
    ushort* kb     = (ushort*)(wsb + (2u << 20) + 16384);          // 16 MB  [32][8192][32]
    ushort* vt     = (ushort*)(wsb + (18u << 20) + 16384);         // 16 MB  [32][32][8192]
    ushort* Abf    = (ushort*)(wsb + (34u << 20) + 16384);         // 32 MB  [32768][512]

    // Attention partials alias Abf (dead after phaseB): 8 MB + 256 KB << 32 MB
    float* Opart = (float*)Abf;                        // [4][32][16][32][32] f32
    float* lpart = Opart + (size_t)4 * 32 * 16 * 1024; // [4][32][16][32] f32

    const float oscale = 0.2550540226496112f;   // log2(e)/sqrt(32): log2-domain softmax

    phaseA_kernel<<<8832, 256, 0, stream>>>(inputs, ln2g, ln2b, Abf,
                                            hidden, mean_h, rstd_h,
                                            Wq, Wk, Wv, WtQ, WtKV);
    phaseB_kernel<<<1152, 256, 0, stream>>>(Abf, WtKV, bk, bv, kb, vt,
                                            hidden, mean_h, rstd_h, ln1g, ln1b,
                                            WtQ, bq, qb, oscale);
    attn_mfma_kernel<<<2048, 256, 0, stream>>>(qb, kb, vt, Opart, lpart);
    attn_combine_kernel<<<512, 256, 0, stream>>>(Opart, lpart, out);
}

// Round 6
// 215.816 us; speedup vs baseline: 1.0147x; 1.0147x over previous
//
#include <hip/hip_runtime.h>
#include <hip/hip_bf16.h>
#include <math.h>

// Problem constants
#define NB    4
#define LQ    512
#define LKV   8192
#define QDIM  1024
#define KVDIM 512
#define NH    8
#define EPS_LN 1e-5f
#define SMAX  12.0f     // fixed softmax baseline (log2 domain); scores*log2e max ~9

typedef __attribute__((ext_vector_type(8))) short bf16x8;
typedef __attribute__((ext_vector_type(4))) float f32x4;

static __device__ __forceinline__ ushort f2bf(float x) {
    unsigned int u = __builtin_bit_cast(unsigned int, x);
    u += 0x7FFFu + ((u >> 16) & 1u);          // round-to-nearest-even
    return (ushort)(u >> 16);
}

#if __has_builtin(__builtin_amdgcn_cvt_pk_bf16_f32)
static __device__ __forceinline__ unsigned int pk_bf16(float a, float b) {
    auto r = __builtin_amdgcn_cvt_pk_bf16_f32(a, b);
    return __builtin_bit_cast(unsigned int, r);
}
#else
static __device__ __forceinline__ unsigned int pk_bf16(float a, float b) {
    return (unsigned int)f2bf(a) | ((unsigned int)f2bf(b) << 16);
}
#endif

#if __has_builtin(__builtin_amdgcn_exp2f)
#define EXP2F(x) __builtin_amdgcn_exp2f(x)
#else
#define EXP2F(x) exp2f(x)
#endif

// In-register 4-row interleave across 16-lane groups:
//   x in rows [a0,a1,a2,a3], y in rows [b0,b1,b2,b3]  (rows = 16-lane groups)
//   -> x = [a0,a2,b0,b2], y = [a1,a3,b1,b3]
// Used to convert the MFMA C/D row grouping (lg*4+r) into the K=32 B-operand
// grouping (lg*8+j) without touching LDS. permlane*_swap are full-rate VALU.
static __device__ __forceinline__ void interleave_swap(unsigned int &x, unsigned int &y, int lane) {
#if __has_builtin(__builtin_amdgcn_permlane32_swap) && __has_builtin(__builtin_amdgcn_permlane16_swap)
    {
        auto r1 = __builtin_amdgcn_permlane32_swap(x, y, false, false);
        auto r2 = __builtin_amdgcn_permlane16_swap(r1[0], r1[1], false, false);
        x = (unsigned int)r2[0];
        y = (unsigned int)r2[1];
    }
#else
    {
        // pl32swap: A2={x.r0,x.r1,y.r0,y.r1}, C2={x.r2,x.r3,y.r2,y.r3}
        unsigned int xs = (unsigned int)__shfl_xor((int)x, 32, 64);
        unsigned int ys = (unsigned int)__shfl_xor((int)y, 32, 64);
        unsigned int A2 = (lane & 32) ? ys : x;
        unsigned int C2 = (lane & 32) ? y  : xs;
        // pl16swap: x'={A2.r0,C2.r0,A2.r2,C2.r2}, y'={A2.r1,C2.r1,A2.r3,C2.r3}
        unsigned int A2x = (unsigned int)__shfl_xor((int)A2, 16, 64);
        unsigned int C2x = (unsigned int)__shfl_xor((int)C2, 16, 64);
        x = (lane & 16) ? C2x : A2;
        y = (lane & 16) ? C2  : A2x;
    }
#endif
}

// async global->LDS, 16B per lane; LDS dest = wave base + lane*16
static __device__ __forceinline__ void gld_lds16(const ushort* g, ushort* l) {
    __builtin_amdgcn_global_load_lds(
        (const __attribute__((address_space(1))) unsigned int*)g,
        (__attribute__((address_space(3))) unsigned int*)l, 16, 0, 0);
}

// ---------------------------------------------------------------------------
// LN normalize one row -> bf16 (wave per row).
// ---------------------------------------------------------------------------
template<int K>
static __device__ __forceinline__ void ln_norm_row(
    const float* __restrict__ x, const float* __restrict__ g,
    const float* __restrict__ bta, ushort* __restrict__ y, int row, int lane)
{
    const float* xp = x + (size_t)row * K;
    constexpr int NV = K / 256;
    float4 v[NV];
    float s = 0.f;
#pragma unroll
    for (int i = 0; i < NV; ++i) {
        v[i] = *(const float4*)(xp + lane * 4 + i * 256);
        s += v[i].x + v[i].y + v[i].z + v[i].w;
    }
#pragma unroll
    for (int o = 1; o < 64; o <<= 1) s += __shfl_xor(s, o, 64);
    const float mu = s * (1.0f / K);
    float vs = 0.f;
#pragma unroll
    for (int i = 0; i < NV; ++i) {
        float dx = v[i].x - mu, dy = v[i].y - mu, dz = v[i].z - mu, dw = v[i].w - mu;
        vs += dx * dx + dy * dy + dz * dz + dw * dw;
    }
#pragma unroll
    for (int o = 1; o < 64; o <<= 1) vs += __shfl_xor(vs, o, 64);
    const float rs = rsqrtf(vs * (1.0f / K) + EPS_LN);
#pragma unroll
    for (int i = 0; i < NV; ++i) {
        const float4 gv = *(const float4*)(g   + lane * 4 + i * 256);
        const float4 bv = *(const float4*)(bta + lane * 4 + i * 256);
        uint2 o;
        o.x = pk_bf16((v[i].x - mu) * rs * gv.x + bv.x, (v[i].y - mu) * rs * gv.y + bv.y);
        o.y = pk_bf16((v[i].z - mu) * rs * gv.z + bv.z, (v[i].w - mu) * rs * gv.w + bv.w);
        *(uint2*)(y + (size_t)row * K + lane * 4 + i * 256) = o;
    }
}

// LN stats only (K=1024), wave per row.
static __device__ __forceinline__ void ln_stats_row(
    const float* __restrict__ x, float* __restrict__ mean, float* __restrict__ rstd,
    int row, int lane)
{
    const float* xp = x + (size_t)row * QDIM;
    float4 v[4];
    float s = 0.f;
#pragma unroll
    for (int i = 0; i < 4; ++i) {
        v[i] = *(const float4*)(xp + lane * 4 + i * 256);
        s += v[i].x + v[i].y + v[i].z + v[i].w;
    }
#pragma unroll
    for (int o = 1; o < 64; o <<= 1) s += __shfl_xor(s, o, 64);
    const float mu = s * (1.0f / QDIM);
    float vs = 0.f;
#pragma unroll
    for (int i = 0; i < 4; ++i) {
        float dx = v[i].x - mu, dy = v[i].y - mu, dz = v[i].z - mu, dw = v[i].w - mu;
        vs += dx * dx + dy * dy + dz * dz + dw * dw;
    }
#pragma unroll
    for (int o = 1; o < 64; o <<= 1) vs += __shfl_xor(vs, o, 64);
    if (lane == 0) {
        mean[row] = mu;
        rstd[row] = rsqrtf(vs * (1.0f / QDIM) + EPS_LN);
    }
}

// 64x64 transpose tile: dst[n][k] = bf16(src[k][n]), src is [K][256].
static __device__ __forceinline__ void wt_transpose_body(
    const float* __restrict__ src, ushort* __restrict__ dst, int K,
    int kx, int ny, int t, ushort (*Ts)[72])
{
    const int k0 = kx * 64, n0 = ny * 64;
    const int nl = t & 63;
#pragma unroll
    for (int p = 0; p < 16; ++p) {
        const int kl = p * 4 + (t >> 6);
        Ts[nl][kl] = f2bf(src[(size_t)(k0 + kl) * 256 + n0 + nl]);
    }
    __syncthreads();
    const int ck = (t & 7) * 8;
#pragma unroll
    for (int p = 0; p < 2; ++p) {
        const int rn = p * 32 + (t >> 3);
        *(bf16x8*)(dst + (size_t)(n0 + rn) * K + k0 + ck) = *(const bf16x8*)&Ts[rn][ck];
    }
}

// ---------------------------------------------------------------------------
// Phase A (one launch): KV normalize (8192 blk) + Q LN stats (512 blk)
// + Wq/Wk/Wv transposes (64+32+32 blk). 256 threads.
// ---------------------------------------------------------------------------
__global__ __launch_bounds__(256) void phaseA_kernel(
    const float* __restrict__ inputs, const float* __restrict__ ln2g,
    const float* __restrict__ ln2b,   ushort* __restrict__ Abf,
    const float* __restrict__ hidden, float* __restrict__ mean_h, float* __restrict__ rstd_h,
    const float* __restrict__ Wq, const float* __restrict__ Wk, const float* __restrict__ Wv,
    ushort* __restrict__ WtQ, ushort* __restrict__ WtKV)
{
    __shared__ ushort Ts[64][72];
    const int bid = blockIdx.x;
    const int t = threadIdx.x;
    const int lane = t & 63;
    if (bid < 8192) {
        ln_norm_row<KVDIM>(inputs, ln2g, ln2b, Abf, bid * 4 + (t >> 6), lane);
    } else if (bid < 8704) {
        ln_stats_row(hidden, mean_h, rstd_h, (bid - 8192) * 4 + (t >> 6), lane);
    } else if (bid < 8768) {
        const int p = bid - 8704;
        wt_transpose_body(Wq, WtQ, QDIM, p & 15, p >> 4, t, Ts);
    } else if (bid < 8800) {
        const int p = bid - 8768;
        wt_transpose_body(Wk, WtKV, KVDIM, p & 7, p >> 3, t, Ts);
    } else {
        const int p = bid - 8800;
        wt_transpose_body(Wv, WtKV + (size_t)256 * KVDIM, KVDIM, p & 7, p >> 3, t, Ts);
    }
}

// ---------------------------------------------------------------------------
// Phase B (one launch, 256 thr): blocks [0,1024) = KV GEMM (128x128, BK=64),
// blocks [1024,1152) = Q GEMM (64x64, BK=64, LN fused into A staging).
// KV GEMM now uses BK=64 (32 MFMA per barrier pair instead of 16) with the
// same 32-row x 64-col staging + xor swizzle already proven in the Q branch.
// Both K and V epilogues go through per-wave LDS transpose -> 16B stores.
// ---------------------------------------------------------------------------
__global__ __launch_bounds__(256) void phaseB_kernel(
    const ushort* __restrict__ Abf, const ushort* __restrict__ WtKV,
    const float* __restrict__ bk, const float* __restrict__ bv,
    ushort* __restrict__ kb, ushort* __restrict__ vt,
    const float* __restrict__ hidden, const float* __restrict__ mean_h,
    const float* __restrict__ rstd_h,
    const float* __restrict__ ln1g, const float* __restrict__ ln1b,
    const ushort* __restrict__ WtQ, const float* __restrict__ bq,
    ushort* __restrict__ qb, float oscale)
{
    __shared__ __align__(16) ushort SMEM[4 * 64 * 72];   // 36864 B
    const int bid  = blockIdx.x;
    const int t    = threadIdx.x;
    const int lane = t & 63;
    const int w    = t >> 6;
    const int lq   = lane & 15;
    const int lg   = lane >> 4;
    const int wm   = w >> 1;
    const int wn   = w & 1;

    if (bid < 1024) {
        // ================= KV GEMM (BK=64) =================
        const int bm = (bid >> 2) * 128;
        const int bn = (bid & 3) * 128;
        ushort* As = SMEM;            // [128][64] swizzled, 8192 ushorts
        ushort* Bs = SMEM + 8192;     // [128][64] swizzled

        const int srow = t >> 3;                              // 0..31
        const int scol = ((t & 7) ^ (srow & 7)) * 8;          // xor-swizzled col
        const ushort* gA = Abf  + (size_t)(bm + srow) * KVDIM + scol;
        const ushort* gB = WtKV + (size_t)(bn + srow) * KVDIM + scol;

        f32x4 acc[4][4] = {};
        for (int k0 = 0; k0 < KVDIM; k0 += 64) {
#pragma unroll
            for (int p = 0; p < 4; ++p) {
                gld_lds16(gA + (size_t)(p * 32) * KVDIM + k0, As + p * 2048 + t * 8);
                gld_lds16(gB + (size_t)(p * 32) * KVDIM + k0, Bs + p * 2048 + t * 8);
            }
            __syncthreads();
#pragma unroll
            for (int kh = 0; kh < 2; ++kh) {
                bf16x8 af[4], bf[4];
#pragma unroll
                for (int mt = 0; mt < 4; ++mt) {
                    const int m = wm * 64 + mt * 16 + lq;
                    af[mt] = *(const bf16x8*)(As + m * 64 + (((lg + 4 * kh) ^ (m & 7)) << 3));
                }
#pragma unroll
                for (int nt = 0; nt < 4; ++nt) {
                    const int n = wn * 64 + nt * 16 + lq;
                    bf[nt] = *(const bf16x8*)(Bs + n * 64 + (((lg + 4 * kh) ^ (n & 7)) << 3));
                }
#pragma unroll
                for (int mt = 0; mt < 4; ++mt)
#pragma unroll
                    for (int nt = 0; nt < 4; ++nt)
                        acc[mt][nt] = __builtin_amdgcn_mfma_f32_16x16x32_bf16(af[mt], bf[nt], acc[mt][nt], 0, 0, 0);
            }
            __syncthreads();
        }
        // After the final barrier all As/Bs reads are done; per-wave Cs regions
        // (which overlap As/Bs) are safe — per-wave use only.
        const int m0base = bm + wm * 64;
        const int bidx   = m0base >> 13;
        const int tokb   = m0base & 8191;

        if (bn < 256) {
            // ---- K path: LDS transpose Cs[tok_l][n_l] -> 16B row stores ----
            ushort (*Cs)[72] = (ushort(*)[72])(SMEM + w * 64 * 72);
#pragma unroll
            for (int nt = 0; nt < 4; ++nt) {
                const int n_l = nt * 16 + lq;
                const float bias = bk[bn + wn * 64 + n_l];
#pragma unroll
                for (int mt = 0; mt < 4; ++mt)
#pragma unroll
                    for (int r = 0; r < 4; ++r)
                        Cs[mt * 16 + lg * 4 + r][n_l] = f2bf(acc[mt][nt][r] + bias);
            }
            const int r0 = lane >> 3;
            const int ck = (lane & 7) * 8;
            const int nc = bn + wn * 64 + ck;
            const int h = nc >> 5, d = nc & 31;
            const size_t obase = (((size_t)(bidx * NH + h) << 13) + tokb) * 32 + d;
#pragma unroll
            for (int p = 0; p < 8; ++p) {
                const int row = p * 8 + r0;
                *(bf16x8*)(kb + obase + (size_t)row * 32) = *(const bf16x8*)&Cs[row][ck];
            }
        } else {
            // ---- V path: vT[bh][d][tok] via per-wave LDS transpose ----
            ushort (*Cs)[72] = (ushort(*)[72])(SMEM + w * 64 * 72);
#pragma unroll
            for (int nt = 0; nt < 4; ++nt) {
                const int n_l = nt * 16 + lq;
                const float bias = bv[(bn - 256) + wn * 64 + n_l];
#pragma unroll
                for (int mt = 0; mt < 4; ++mt) {
                    uint2 o;
                    o.x = pk_bf16(acc[mt][nt][0] + bias, acc[mt][nt][1] + bias);
                    o.y = pk_bf16(acc[mt][nt][2] + bias, acc[mt][nt][3] + bias);
                    *(uint2*)&Cs[n_l][mt * 16 + lg * 4] = o;
                }
            }
            const int r0 = lane >> 3;
            const int cm = (lane & 7) * 8;
            const int tokc = tokb + cm;
#pragma unroll
            for (int p = 0; p < 8; ++p) {
                const int row = p * 8 + r0;
                const int nv  = (bn - 256) + wn * 64 + row;
                const int h = nv >> 5, d = nv & 31;
                *(bf16x8*)(vt + ((size_t)(bidx * NH + h) * 32 + d) * LKV + tokc) =
                    *(const bf16x8*)&Cs[row][cm];
            }
        }
    } else {
        // ================= Q GEMM (LN fused) =================
        const int p  = bid - 1024;
        const int bm = (p >> 2) * 64;
        const int bn = (p & 3) * 64;
        ushort* As = SMEM;
        ushort* Bs = SMEM + 4096;

        const int srow = t >> 3;                              // 0..31
        const int scol = ((t & 7) ^ (srow & 7)) * 8;          // xor-swizzled col
        const ushort* gB = WtQ + (size_t)(bn + srow) * QDIM + scol;
        ushort* lB  = Bs + t * 8;
        ushort* lA0 = As + t * 8;
        ushort* lA1 = As + 2048 + t * 8;

        const int r0 = bm + srow;
        const float mu0 = mean_h[r0],      rs0 = rstd_h[r0];
        const float mu1 = mean_h[r0 + 32], rs1 = rstd_h[r0 + 32];
        const float* xA0 = hidden + (size_t)r0 * QDIM + scol;
        const float* xA1 = xA0 + (size_t)32 * QDIM;

        f32x4 acc[2][2] = {};
        for (int k0 = 0; k0 < QDIM; k0 += 64) {
            gld_lds16(gB + k0,                      lB);
            gld_lds16(gB + (size_t)32 * QDIM + k0,  lB + 2048);
            const float4 a0 = *(const float4*)(xA0 + k0);
            const float4 a1 = *(const float4*)(xA0 + k0 + 4);
            const float4 c0 = *(const float4*)(xA1 + k0);
            const float4 c1 = *(const float4*)(xA1 + k0 + 4);
            const float4 g0 = *(const float4*)(ln1g + k0 + scol);
            const float4 g1 = *(const float4*)(ln1g + k0 + scol + 4);
            const float4 d0 = *(const float4*)(ln1b + k0 + scol);
            const float4 d1 = *(const float4*)(ln1b + k0 + scol + 4);
            uint4 w0, w1;
            w0.x = pk_bf16((a0.x - mu0) * rs0 * g0.x + d0.x, (a0.y - mu0) * rs0 * g0.y + d0.y);
            w0.y = pk_bf16((a0.z - mu0) * rs0 * g0.z + d0.z, (a0.w - mu0) * rs0 * g0.w + d0.w);
            w0.z = pk_bf16((a1.x - mu0) * rs0 * g1.x + d1.x, (a1.y - mu0) * rs0 * g1.y + d1.y);
            w0.w = pk_bf16((a1.z - mu0) * rs0 * g1.z + d1.z, (a1.w - mu0) * rs0 * g1.w + d1.w);
            w1.x = pk_bf16((c0.x - mu1) * rs1 * g0.x + d0.x, (c0.y - mu1) * rs1 * g0.y + d0.y);
            w1.y = pk_bf16((c0.z - mu1) * rs1 * g0.z + d0.z, (c0.w - mu1) * rs1 * g0.w + d0.w);
            w1.z = pk_bf16((c1.x - mu1) * rs1 * g1.x + d1.x, (c1.y - mu1) * rs1 * g1.y + d1.y);
            w1.w = pk_bf16((c1.z - mu1) * rs1 * g1.z + d1.z, (c1.w - mu1) * rs1 * g1.w + d1.w);
            *(uint4*)lA0 = w0;
            *(uint4*)lA1 = w1;
            __syncthreads();
#pragma unroll
            for (int kh = 0; kh < 2; ++kh) {
                bf16x8 af[2], bf[2];
#pragma unroll
                for (int mt = 0; mt < 2; ++mt) {
                    const int m = wm * 32 + mt * 16 + lq;
                    af[mt] = *(const bf16x8*)(As + m * 64 + (((lg + 4 * kh) ^ (m & 7)) << 3));
                }
#pragma unroll
                for (int nt = 0; nt < 2; ++nt) {
                    const int n = wn * 32 + nt * 16 + lq;
                    bf[nt] = *(const bf16x8*)(Bs + n * 64 + (((lg + 4 * kh) ^ (n & 7)) << 3));
                }
#pragma unroll
                for (int mt = 0; mt < 2; ++mt)
#pragma unroll
                    for (int nt = 0; nt < 2; ++nt)
                        acc[mt][nt] = __builtin_amdgcn_mfma_f32_16x16x32_bf16(af[mt], bf[nt], acc[mt][nt], 0, 0, 0);
            }
            __syncthreads();
        }

#pragma unroll
        for (int nt = 0; nt < 2; ++nt) {
            const int n = bn + wn * 32 + nt * 16 + lq;
            const int h = n >> 5, d = n & 31;
            const float bias = bq[n];
#pragma unroll
            for (int mt = 0; mt < 2; ++mt) {
                const int m0   = bm + wm * 32 + mt * 16 + lg * 4;
                const int bidx = m0 >> 9;
                const int tok  = m0 & 511;
                const size_t base = (((size_t)(bidx * NH + h) << 9) + tok) * 32 + d;
#pragma unroll
                for (int r = 0; r < 4; ++r)
                    qb[base + (size_t)r * 32] = f2bf((acc[mt][nt][r] + bias) * oscale);
            }
        }
    }
}

// ---------------------------------------------------------------------------
// MFMA flash attention, fixed-baseline softmax, q-tile 32, 64-KV iterations.
// Inner loop identical to the proven 52.5us version. L2-LOCALITY lever: the
// 512MB of K/V re-reads (16 qt x 32 bh x 1MB) previously thrashed the 4MB
// per-XCD L2 (co-resident blocks spanned all 4 bh = 4MB working set). New
// dispatch order is bh-major per XCD: u = bid>>3 = bhw*64 + qt*4 + quarter,
// so the ~96 co-resident blocks of an XCD span <=2 bh (<=2MB) -> K/V served
// from L2 (34.5 TB/s) instead of the saturated L3/fabric path (~9.5 TB/s).
// Grid 2048 = 4 bhw x 16 qt x 4 KV-quarters x 8 xcd. Wave w owns KV
// [quarter*2048 + w*512, +512) = 8 iterations. Partials per quarter;
// attn_combine merges 4.
// ---------------------------------------------------------------------------
__global__ __launch_bounds__(256, 4) void attn_mfma_kernel(
    const ushort* __restrict__ Qb,  // [B*H][LQ][32] bf16, pre-scaled by log2e/sqrt(32)
    const ushort* __restrict__ Kb,  // [B*H][LKV][32]
    const ushort* __restrict__ Vt,  // [B*H][32][LKV]
    float* __restrict__ Opart,      // [4][32][16][32q][32d] f32 partials
    float* __restrict__ lpart)      // [4][32][16][32q] f32 partials
{
    const int bid = blockIdx.x;
    const int xcd = bid & 7;
    const int u   = bid >> 3;                // 0..255, sequential within an XCD
    const int bhw = u >> 6;                  // 0..3  bh-within-XCD (MAJOR)
    const int r2  = u & 63;
    const int qt  = r2 >> 2;                 // 0..15 (q-tile of 32)
    const int quarter = r2 & 3;              // 0..3: KV quarter [q*2048, +2048)
    const int bh  = (bhw << 3) | xcd;        // bh pinned to one XCD
    const int t = threadIdx.x, w = t >> 6, lane = t & 63;
    const int lq = lane & 15, lg = lane >> 4;

    __shared__ __align__(16) float Ob[2 * 32 * 36];   // 9216 B combine scratch
    __shared__ float lbuf[4][32];

    // Q frags (B operand of QK): lane holds Q[q=n*16+lq][k=lg*8+j]
    bf16x8 qfrag[2];
    const size_t qbase = ((size_t)bh * LQ + qt * 32) * 32;
    qfrag[0] = *(const bf16x8*)(Qb + qbase + (size_t)lq * 32 + lg * 8);
    qfrag[1] = *(const bf16x8*)(Qb + qbase + (size_t)(16 + lq) * 32 + lg * 8);

    const int kv0 = quarter * 2048 + w * 512;
    const ushort* KpA = Kb + ((size_t)bh * LKV + kv0 + lq) * 32 + lg * 8;
    const ushort* VpA = Vt + ((size_t)bh * 32 + lq) * LKV + kv0 + lg * 8;

    f32x4 oacc[2][2] = {};        // [d-tile][q-tile]
    float l_part[2] = {0.f, 0.f};
    const f32x4 cM = {-SMAX, -SMAX, -SMAX, -SMAX};

    // prologue: K frags for iter 0 (A operand of QK: lane = K[kv=lq][k=lg*8+j])
    bf16x8 kf[4];
#pragma unroll
    for (int m = 0; m < 4; ++m)
        kf[m] = *(const bf16x8*)(KpA + (size_t)(m * 16) * 32);

    for (int kt = 0; kt < 512; kt += 64) {
        bf16x8 kc[4];
#pragma unroll
        for (int m = 0; m < 4; ++m) kc[m] = kf[m];

        // V frags for THIS iter (A operand of PV): V^T[d=dt*16+lq][kv=kt+hf*32+lg*8+j]
        // issued here, consumed after QK+softmax (~250 cyc) -> L2 latency hidden
        bf16x8 vc[2][2];
#pragma unroll
        for (int dt = 0; dt < 2; ++dt)
#pragma unroll
            for (int hf = 0; hf < 2; ++hf)
                vc[dt][hf] = *(const bf16x8*)(VpA + (size_t)(dt * 16) * LKV + kt + hf * 32);

        // prefetch K frags for NEXT iter (clamp: harmless re-read of kt=0)
        const int nk = (kt + 64 < 512) ? kt + 64 : 0;
#pragma unroll
        for (int m = 0; m < 4; ++m)
            kf[m] = *(const bf16x8*)(KpA + (size_t)(nk + m * 16) * 32);

        // S^T[kv64][q32] = K.Q^T - SMAX   (lane: kv=m*16+lg*4+r, q=n*16+lq)
        f32x4 s[4][2];
#pragma unroll
        for (int m = 0; m < 4; ++m)
#pragma unroll
            for (int n = 0; n < 2; ++n)
                s[m][n] = __builtin_amdgcn_mfma_f32_16x16x32_bf16(kc[m], qfrag[n], cM, 0, 0, 0);

        // exp2 + pack + permlane interleave -> PV B-frags, all in-register.
        // Per (n, kv32-block z): rows-of-pairs A=[p0,p2,p4,p6], B=[p1,p3,p5,p7],
        // C=[p8,p10,p12,p14], D=[p9,p11,p13,p15]; interleave_swap(A,C)->W0,W2;
        // (B,D)->W1,W3; [W0,W1,W2,W3] == B-operand words (kv pair 4*lg+w).
        bf16x8 pf[2][2];
#pragma unroll
        for (int n = 0; n < 2; ++n) {
#pragma unroll
            for (int z = 0; z < 2; ++z) {
                const float e0 = EXP2F(s[2 * z][n][0]);
                const float e1 = EXP2F(s[2 * z][n][1]);
                const float e2 = EXP2F(s[2 * z][n][2]);
                const float e3 = EXP2F(s[2 * z][n][3]);
                const float f0 = EXP2F(s[2 * z + 1][n][0]);
                const float f1 = EXP2F(s[2 * z + 1][n][1]);
                const float f2 = EXP2F(s[2 * z + 1][n][2]);
                const float f3 = EXP2F(s[2 * z + 1][n][3]);
                l_part[n] += ((e0 + e1) + (e2 + e3)) + ((f0 + f1) + (f2 + f3));
                unsigned int wa = pk_bf16(e0, e1);
                unsigned int wb = pk_bf16(e2, e3);
                unsigned int wc = pk_bf16(f0, f1);
                unsigned int wd = pk_bf16(f2, f3);
                interleave_swap(wa, wc, lane);   // wa=W0, wc=W2
                interleave_swap(wb, wd, lane);   // wb=W1, wd=W3
                uint4 wv;
                wv.x = wa; wv.y = wb; wv.z = wc; wv.w = wd;
                pf[n][z] = __builtin_bit_cast(bf16x8, wv);
            }
        }

        // O^T[d32][q32] += V^T . P^T
#pragma unroll
        for (int dt = 0; dt < 2; ++dt)
#pragma unroll
            for (int n = 0; n < 2; ++n) {
                oacc[dt][n] = __builtin_amdgcn_mfma_f32_16x16x32_bf16(vc[dt][0], pf[n][0], oacc[dt][n], 0, 0, 0);
                oacc[dt][n] = __builtin_amdgcn_mfma_f32_16x16x32_bf16(vc[dt][1], pf[n][1], oacc[dt][n], 0, 0, 0);
            }
    }

    // ---- l reduce + 4-wave combine -> partial write ----
#pragma unroll
    for (int n = 0; n < 2; ++n) {
        l_part[n] += __shfl_xor(l_part[n], 16);
        l_part[n] += __shfl_xor(l_part[n], 32);
    }
    if (lg == 0) {
        lbuf[w][lq]      = l_part[0];
        lbuf[w][16 + lq] = l_part[1];
    }
    if (w >= 2) {
#pragma unroll
        for (int n = 0; n < 2; ++n)
#pragma unroll
            for (int dt = 0; dt < 2; ++dt)
                *(f32x4*)&Ob[((size_t)(w - 2) * 32 + n * 16 + lq) * 36 + dt * 16 + lg * 4] = oacc[dt][n];
    }
    __syncthreads();
    if (w < 2) {
#pragma unroll
        for (int n = 0; n < 2; ++n)
#pragma unroll
            for (int dt = 0; dt < 2; ++dt) {
                float* p = &Ob[((size_t)w * 32 + n * 16 + lq) * 36 + dt * 16 + lg * 4];
                f32x4 v = *(f32x4*)p;
                v += oacc[dt][n];
                *(f32x4*)p = v;
            }
    }
    __syncthreads();
    {
        const int pidx = (quarter * 32 + bh) * 16 + qt;
        const int q  = t >> 3;           // 0..31
        const int d0 = (t & 7) * 4;      // 0..28
        f32x4 s0 = *(const f32x4*)&Ob[((size_t)q) * 36 + d0];
        f32x4 s1 = *(const f32x4*)&Ob[((size_t)(32 + q)) * 36 + d0];
        s0 += s1;
        *(f32x4*)(Opart + (size_t)pidx * 1024 + q * 32 + d0) = s0;
        if ((t & 7) == 0) {
            float gl = lbuf[0][q] + lbuf[1][q] + lbuf[2][q] + lbuf[3][q];
            lpart[(size_t)pidx * 32 + q] = gl;
        }
    }
}

// ---------------------------------------------------------------------------
// Combine the 4 KV-quarter partials: Out = sum(Oq)/sum(lq). Grid 512 =
// bh*16+qt, 256 thr, float4 per thread.
// ---------------------------------------------------------------------------
__global__ __launch_bounds__(256) void attn_combine_kernel(
    const float* __restrict__ Opart, const float* __restrict__ lpart,
    float* __restrict__ Out)
{
    const int cb = blockIdx.x;               // 0..511
    const int bh = cb >> 4, qt = cb & 15;
    const int b = bh >> 3, h = bh & 7;
    const int t = threadIdx.x;
    const int q = t >> 3;                    // 0..31
    const int dq = (t & 7) * 4;              // 0..28
    float4 o = {0.f, 0.f, 0.f, 0.f};
    float l = 0.f;
#pragma unroll
    for (int j = 0; j < 4; ++j) {
        const size_t pidx = (size_t)((j * 32 + bh) * 16 + qt);
        const float4 a = *(const float4*)(Opart + pidx * 1024 + q * 32 + dq);
        o.x += a.x; o.y += a.y; o.z += a.z; o.w += a.w;
        l += lpart[pidx * 32 + q];
    }
    const float inv = 1.0f / l;
    o.x *= inv; o.y *= inv; o.z *= inv; o.w *= inv;
    *(float4*)(Out + ((size_t)b * LQ + qt * 32 + q) * 256 + h * 32 + dq) = o;
}

// ---------------------------------------------------------------------------
extern "C" void kernel_launch(void* const* d_in, const int* in_sizes, int n_in,
                              void* d_out, int out_size, void* d_ws, size_t ws_size,
                              hipStream_t stream)
{
    const float* hidden = (const float*)d_in[0];
    const float* inputs = (const float*)d_in[1];
    const float* ln1g   = (const float*)d_in[2];
    const float* ln1b   = (const float*)d_in[3];
    const float* ln2g   = (const float*)d_in[4];
    const float* ln2b   = (const float*)d_in[5];
    const float* Wq     = (const float*)d_in[6];
    const float* bq     = (const float*)d_in[7];
    const float* Wk     = (const float*)d_in[8];
    const float* bk     = (const float*)d_in[9];
    const float* Wv     = (const float*)d_in[10];
    const float* bv     = (const float*)d_in[11];
    float* out = (float*)d_out;

    // workspace (bytes), total ~66 MB
    char* wsb = (char*)d_ws;
    ushort* qb     = (ushort*)(wsb);                               // 1 MB   [32][512][32]
    ushort* WtKV   = (ushort*)(wsb + (1u << 20));                  // 0.5 MB [512][512]
    ushort* WtQ    = (ushort*)(wsb + (1u << 20) + (512u << 10));   // 0.5 MB [256][1024]
    float*  mean_h = (float*)(wsb + (2u << 20));                   // 8 KB
    float*  rstd_h = (float*)(wsb + (2u << 20) + 8192);            // 8 KB
    ushort* kb     = (ushort*)(wsb + (2u << 20) + 16384);          // 16 MB  [32][8192][32]
    ushort* vt     = (ushort*)(wsb + (18u << 20) + 16384);         // 16 MB  [32][32][8192]
    ushort* Abf    = (ushort*)(wsb + (34u << 20) + 16384);         // 32 MB  [32768][512]

    // Attention partials alias Abf (dead after phaseB): 8 MB + 256 KB << 32 MB
    float* Opart = (float*)Abf;                        // [4][32][16][32][32] f32
    float* lpart = Opart + (size_t)4 * 32 * 16 * 1024; // [4][32][16][32] f32

    const float oscale = 0.2550540226496112f;   // log2(e)/sqrt(32): log2-domain softmax

    phaseA_kernel<<<8832, 256, 0, stream>>>(inputs, ln2g, ln2b, Abf,
                                            hidden, mean_h, rstd_h,
                                            Wq, Wk, Wv, WtQ, WtKV);
    phaseB_kernel<<<1152, 256, 0, stream>>>(Abf, WtKV, bk, bv, kb, vt,
                                            hidden, mean_h, rstd_h, ln1g, ln1b,
                                            WtQ, bq, qb, oscale);
    attn_mfma_kernel<<<2048, 256, 0, stream>>>(qb, kb, vt, Opart, lpart);
    attn_combine_kernel<<<512, 256, 0, stream>>>(Opart, lpart, out);
}

// Round 7
// 207.358 us; speedup vs baseline: 1.0561x; 1.0408x over previous
//
#include <hip/hip_runtime.h>
#include <hip/hip_bf16.h>
#include <math.h>

// Problem constants
#define NB    4
#define LQ    512
#define LKV   8192
#define QDIM  1024
#define KVDIM 512
#define NH    8
#define EPS_LN 1e-5f
#define SMAX  12.0f     // fixed softmax baseline (log2 domain); scores*log2e max ~9

typedef __attribute__((ext_vector_type(8))) short bf16x8;
typedef __attribute__((ext_vector_type(4))) float f32x4;

static __device__ __forceinline__ ushort f2bf(float x) {
    unsigned int u = __builtin_bit_cast(unsigned int, x);
    u += 0x7FFFu + ((u >> 16) & 1u);          // round-to-nearest-even
    return (ushort)(u >> 16);
}

#if __has_builtin(__builtin_amdgcn_cvt_pk_bf16_f32)
static __device__ __forceinline__ unsigned int pk_bf16(float a, float b) {
    auto r = __builtin_amdgcn_cvt_pk_bf16_f32(a, b);
    return __builtin_bit_cast(unsigned int, r);
}
#else
static __device__ __forceinline__ unsigned int pk_bf16(float a, float b) {
    return (unsigned int)f2bf(a) | ((unsigned int)f2bf(b) << 16);
}
#endif

#if __has_builtin(__builtin_amdgcn_exp2f)
#define EXP2F(x) __builtin_amdgcn_exp2f(x)
#else
#define EXP2F(x) exp2f(x)
#endif

// In-register 4-row interleave across 16-lane groups:
//   x in rows [a0,a1,a2,a3], y in rows [b0,b1,b2,b3]  (rows = 16-lane groups)
//   -> x = [a0,a2,b0,b2], y = [a1,a3,b1,b3]
// Used to convert the MFMA C/D row grouping (lg*4+r) into the K=32 B-operand
// grouping (lg*8+j) without touching LDS. permlane*_swap are full-rate VALU.
static __device__ __forceinline__ void interleave_swap(unsigned int &x, unsigned int &y, int lane) {
#if __has_builtin(__builtin_amdgcn_permlane32_swap) && __has_builtin(__builtin_amdgcn_permlane16_swap)
    {
        auto r1 = __builtin_amdgcn_permlane32_swap(x, y, false, false);
        auto r2 = __builtin_amdgcn_permlane16_swap(r1[0], r1[1], false, false);
        x = (unsigned int)r2[0];
        y = (unsigned int)r2[1];
    }
#else
    {
        // pl32swap: A2={x.r0,x.r1,y.r0,y.r1}, C2={x.r2,x.r3,y.r2,y.r3}
        unsigned int xs = (unsigned int)__shfl_xor((int)x, 32, 64);
        unsigned int ys = (unsigned int)__shfl_xor((int)y, 32, 64);
        unsigned int A2 = (lane & 32) ? ys : x;
        unsigned int C2 = (lane & 32) ? y  : xs;
        // pl16swap: x'={A2.r0,C2.r0,A2.r2,C2.r2}, y'={A2.r1,C2.r1,A2.r3,C2.r3}
        unsigned int A2x = (unsigned int)__shfl_xor((int)A2, 16, 64);
        unsigned int C2x = (unsigned int)__shfl_xor((int)C2, 16, 64);
        x = (lane & 16) ? C2x : A2;
        y = (lane & 16) ? C2  : A2x;
    }
#endif
}

// async global->LDS, 16B per lane; LDS dest = wave base + lane*16
static __device__ __forceinline__ void gld_lds16(const ushort* g, ushort* l) {
    __builtin_amdgcn_global_load_lds(
        (const __attribute__((address_space(1))) unsigned int*)g,
        (__attribute__((address_space(3))) unsigned int*)l, 16, 0, 0);
}

// ---------------------------------------------------------------------------
// LN normalize one row -> bf16 (wave per row).
// ---------------------------------------------------------------------------
template<int K>
static __device__ __forceinline__ void ln_norm_row(
    const float* __restrict__ x, const float* __restrict__ g,
    const float* __restrict__ bta, ushort* __restrict__ y, int row, int lane)
{
    const float* xp = x + (size_t)row * K;
    constexpr int NV = K / 256;
    float4 v[NV];
    float s = 0.f;
#pragma unroll
    for (int i = 0; i < NV; ++i) {
        v[i] = *(const float4*)(xp + lane * 4 + i * 256);
        s += v[i].x + v[i].y + v[i].z + v[i].w;
    }
#pragma unroll
    for (int o = 1; o < 64; o <<= 1) s += __shfl_xor(s, o, 64);
    const float mu = s * (1.0f / K);
    float vs = 0.f;
#pragma unroll
    for (int i = 0; i < NV; ++i) {
        float dx = v[i].x - mu, dy = v[i].y - mu, dz = v[i].z - mu, dw = v[i].w - mu;
        vs += dx * dx + dy * dy + dz * dz + dw * dw;
    }
#pragma unroll
    for (int o = 1; o < 64; o <<= 1) vs += __shfl_xor(vs, o, 64);
    const float rs = rsqrtf(vs * (1.0f / K) + EPS_LN);
#pragma unroll
    for (int i = 0; i < NV; ++i) {
        const float4 gv = *(const float4*)(g   + lane * 4 + i * 256);
        const float4 bv = *(const float4*)(bta + lane * 4 + i * 256);
        uint2 o;
        o.x = pk_bf16((v[i].x - mu) * rs * gv.x + bv.x, (v[i].y - mu) * rs * gv.y + bv.y);
        o.y = pk_bf16((v[i].z - mu) * rs * gv.z + bv.z, (v[i].w - mu) * rs * gv.w + bv.w);
        *(uint2*)(y + (size_t)row * K + lane * 4 + i * 256) = o;
    }
}

// LN stats only (K=1024), wave per row.
static __device__ __forceinline__ void ln_stats_row(
    const float* __restrict__ x, float* __restrict__ mean, float* __restrict__ rstd,
    int row, int lane)
{
    const float* xp = x + (size_t)row * QDIM;
    float4 v[4];
    float s = 0.f;
#pragma unroll
    for (int i = 0; i < 4; ++i) {
        v[i] = *(const float4*)(xp + lane * 4 + i * 256);
        s += v[i].x + v[i].y + v[i].z + v[i].w;
    }
#pragma unroll
    for (int o = 1; o < 64; o <<= 1) s += __shfl_xor(s, o, 64);
    const float mu = s * (1.0f / QDIM);
    float vs = 0.f;
#pragma unroll
    for (int i = 0; i < 4; ++i) {
        float dx = v[i].x - mu, dy = v[i].y - mu, dz = v[i].z - mu, dw = v[i].w - mu;
        vs += dx * dx + dy * dy + dz * dz + dw * dw;
    }
#pragma unroll
    for (int o = 1; o < 64; o <<= 1) vs += __shfl_xor(vs, o, 64);
    if (lane == 0) {
        mean[row] = mu;
        rstd[row] = rsqrtf(vs * (1.0f / QDIM) + EPS_LN);
    }
}

// 64x64 transpose tile: dst[n][k] = bf16(src[k][n]), src is [K][256].
static __device__ __forceinline__ void wt_transpose_body(
    const float* __restrict__ src, ushort* __restrict__ dst, int K,
    int kx, int ny, int t, ushort (*Ts)[72])
{
    const int k0 = kx * 64, n0 = ny * 64;
    const int nl = t & 63;
#pragma unroll
    for (int p = 0; p < 16; ++p) {
        const int kl = p * 4 + (t >> 6);
        Ts[nl][kl] = f2bf(src[(size_t)(k0 + kl) * 256 + n0 + nl]);
    }
    __syncthreads();
    const int ck = (t & 7) * 8;
#pragma unroll
    for (int p = 0; p < 2; ++p) {
        const int rn = p * 32 + (t >> 3);
        *(bf16x8*)(dst + (size_t)(n0 + rn) * K + k0 + ck) = *(const bf16x8*)&Ts[rn][ck];
    }
}

// ---------------------------------------------------------------------------
// Phase A (one launch): KV normalize (8192 blk) + Q LN stats (512 blk)
// + Wq/Wk/Wv transposes (64+32+32 blk). 256 threads.
// ---------------------------------------------------------------------------
__global__ __launch_bounds__(256) void phaseA_kernel(
    const float* __restrict__ inputs, const float* __restrict__ ln2g,
    const float* __restrict__ ln2b,   ushort* __restrict__ Abf,
    const float* __restrict__ hidden, float* __restrict__ mean_h, float* __restrict__ rstd_h,
    const float* __restrict__ Wq, const float* __restrict__ Wk, const float* __restrict__ Wv,
    ushort* __restrict__ WtQ, ushort* __restrict__ WtKV)
{
    __shared__ ushort Ts[64][72];
    const int bid = blockIdx.x;
    const int t = threadIdx.x;
    const int lane = t & 63;
    if (bid < 8192) {
        ln_norm_row<KVDIM>(inputs, ln2g, ln2b, Abf, bid * 4 + (t >> 6), lane);
    } else if (bid < 8704) {
        ln_stats_row(hidden, mean_h, rstd_h, (bid - 8192) * 4 + (t >> 6), lane);
    } else if (bid < 8768) {
        const int p = bid - 8704;
        wt_transpose_body(Wq, WtQ, QDIM, p & 15, p >> 4, t, Ts);
    } else if (bid < 8800) {
        const int p = bid - 8768;
        wt_transpose_body(Wk, WtKV, KVDIM, p & 7, p >> 3, t, Ts);
    } else {
        const int p = bid - 8800;
        wt_transpose_body(Wv, WtKV + (size_t)256 * KVDIM, KVDIM, p & 7, p >> 3, t, Ts);
    }
}

// ---------------------------------------------------------------------------
// Phase B (one launch, 256 thr): blocks [0,1024) = KV GEMM (128x128, BK=64),
// blocks [1024,1152) = Q GEMM (64x64, BK=64, LN fused into A staging).
// Both K and V epilogues go through per-wave LDS transpose -> 16B stores.
// ---------------------------------------------------------------------------
__global__ __launch_bounds__(256) void phaseB_kernel(
    const ushort* __restrict__ Abf, const ushort* __restrict__ WtKV,
    const float* __restrict__ bk, const float* __restrict__ bv,
    ushort* __restrict__ kb, ushort* __restrict__ vt,
    const float* __restrict__ hidden, const float* __restrict__ mean_h,
    const float* __restrict__ rstd_h,
    const float* __restrict__ ln1g, const float* __restrict__ ln1b,
    const ushort* __restrict__ WtQ, const float* __restrict__ bq,
    ushort* __restrict__ qb, float oscale)
{
    __shared__ __align__(16) ushort SMEM[4 * 64 * 72];   // 36864 B
    const int bid  = blockIdx.x;
    const int t    = threadIdx.x;
    const int lane = t & 63;
    const int w    = t >> 6;
    const int lq   = lane & 15;
    const int lg   = lane >> 4;
    const int wm   = w >> 1;
    const int wn   = w & 1;

    if (bid < 1024) {
        // ================= KV GEMM (BK=64) =================
        const int bm = (bid >> 2) * 128;
        const int bn = (bid & 3) * 128;
        ushort* As = SMEM;            // [128][64] swizzled, 8192 ushorts
        ushort* Bs = SMEM + 8192;     // [128][64] swizzled

        const int srow = t >> 3;                              // 0..31
        const int scol = ((t & 7) ^ (srow & 7)) * 8;          // xor-swizzled col
        const ushort* gA = Abf  + (size_t)(bm + srow) * KVDIM + scol;
        const ushort* gB = WtKV + (size_t)(bn + srow) * KVDIM + scol;

        f32x4 acc[4][4] = {};
        for (int k0 = 0; k0 < KVDIM; k0 += 64) {
#pragma unroll
            for (int p = 0; p < 4; ++p) {
                gld_lds16(gA + (size_t)(p * 32) * KVDIM + k0, As + p * 2048 + t * 8);
                gld_lds16(gB + (size_t)(p * 32) * KVDIM + k0, Bs + p * 2048 + t * 8);
            }
            __syncthreads();
#pragma unroll
            for (int kh = 0; kh < 2; ++kh) {
                bf16x8 af[4], bf[4];
#pragma unroll
                for (int mt = 0; mt < 4; ++mt) {
                    const int m = wm * 64 + mt * 16 + lq;
                    af[mt] = *(const bf16x8*)(As + m * 64 + (((lg + 4 * kh) ^ (m & 7)) << 3));
                }
#pragma unroll
                for (int nt = 0; nt < 4; ++nt) {
                    const int n = wn * 64 + nt * 16 + lq;
                    bf[nt] = *(const bf16x8*)(Bs + n * 64 + (((lg + 4 * kh) ^ (n & 7)) << 3));
                }
#pragma unroll
                for (int mt = 0; mt < 4; ++mt)
#pragma unroll
                    for (int nt = 0; nt < 4; ++nt)
                        acc[mt][nt] = __builtin_amdgcn_mfma_f32_16x16x32_bf16(af[mt], bf[nt], acc[mt][nt], 0, 0, 0);
            }
            __syncthreads();
        }
        // After the final barrier all As/Bs reads are done; per-wave Cs regions
        // (which overlap As/Bs) are safe — per-wave use only.
        const int m0base = bm + wm * 64;
        const int bidx   = m0base >> 13;
        const int tokb   = m0base & 8191;

        if (bn < 256) {
            // ---- K path: LDS transpose Cs[tok_l][n_l] -> 16B row stores ----
            ushort (*Cs)[72] = (ushort(*)[72])(SMEM + w * 64 * 72);
#pragma unroll
            for (int nt = 0; nt < 4; ++nt) {
                const int n_l = nt * 16 + lq;
                const float bias = bk[bn + wn * 64 + n_l];
#pragma unroll
                for (int mt = 0; mt < 4; ++mt)
#pragma unroll
                    for (int r = 0; r < 4; ++r)
                        Cs[mt * 16 + lg * 4 + r][n_l] = f2bf(acc[mt][nt][r] + bias);
            }
            const int r0 = lane >> 3;
            const int ck = (lane & 7) * 8;
            const int nc = bn + wn * 64 + ck;
            const int h = nc >> 5, d = nc & 31;
            const size_t obase = (((size_t)(bidx * NH + h) << 13) + tokb) * 32 + d;
#pragma unroll
            for (int p = 0; p < 8; ++p) {
                const int row = p * 8 + r0;
                *(bf16x8*)(kb + obase + (size_t)row * 32) = *(const bf16x8*)&Cs[row][ck];
            }
        } else {
            // ---- V path: vT[bh][d][tok] via per-wave LDS transpose ----
            ushort (*Cs)[72] = (ushort(*)[72])(SMEM + w * 64 * 72);
#pragma unroll
            for (int nt = 0; nt < 4; ++nt) {
                const int n_l = nt * 16 + lq;
                const float bias = bv[(bn - 256) + wn * 64 + n_l];
#pragma unroll
                for (int mt = 0; mt < 4; ++mt) {
                    uint2 o;
                    o.x = pk_bf16(acc[mt][nt][0] + bias, acc[mt][nt][1] + bias);
                    o.y = pk_bf16(acc[mt][nt][2] + bias, acc[mt][nt][3] + bias);
                    *(uint2*)&Cs[n_l][mt * 16 + lg * 4] = o;
                }
            }
            const int r0 = lane >> 3;
            const int cm = (lane & 7) * 8;
            const int tokc = tokb + cm;
#pragma unroll
            for (int p = 0; p < 8; ++p) {
                const int row = p * 8 + r0;
                const int nv  = (bn - 256) + wn * 64 + row;
                const int h = nv >> 5, d = nv & 31;
                *(bf16x8*)(vt + ((size_t)(bidx * NH + h) * 32 + d) * LKV + tokc) =
                    *(const bf16x8*)&Cs[row][cm];
            }
        }
    } else {
        // ================= Q GEMM (LN fused) =================
        const int p  = bid - 1024;
        const int bm = (p >> 2) * 64;
        const int bn = (p & 3) * 64;
        ushort* As = SMEM;
        ushort* Bs = SMEM + 4096;

        const int srow = t >> 3;                              // 0..31
        const int scol = ((t & 7) ^ (srow & 7)) * 8;          // xor-swizzled col
        const ushort* gB = WtQ + (size_t)(bn + srow) * QDIM + scol;
        ushort* lB  = Bs + t * 8;
        ushort* lA0 = As + t * 8;
        ushort* lA1 = As + 2048 + t * 8;

        const int r0 = bm + srow;
        const float mu0 = mean_h[r0],      rs0 = rstd_h[r0];
        const float mu1 = mean_h[r0 + 32], rs1 = rstd_h[r0 + 32];
        const float* xA0 = hidden + (size_t)r0 * QDIM + scol;
        const float* xA1 = xA0 + (size_t)32 * QDIM;

        f32x4 acc[2][2] = {};
        for (int k0 = 0; k0 < QDIM; k0 += 64) {
            gld_lds16(gB + k0,                      lB);
            gld_lds16(gB + (size_t)32 * QDIM + k0,  lB + 2048);
            const float4 a0 = *(const float4*)(xA0 + k0);
            const float4 a1 = *(const float4*)(xA0 + k0 + 4);
            const float4 c0 = *(const float4*)(xA1 + k0);
            const float4 c1 = *(const float4*)(xA1 + k0 + 4);
            const float4 g0 = *(const float4*)(ln1g + k0 + scol);
            const float4 g1 = *(const float4*)(ln1g + k0 + scol + 4);
            const float4 d0 = *(const float4*)(ln1b + k0 + scol);
            const float4 d1 = *(const float4*)(ln1b + k0 + scol + 4);
            uint4 w0, w1;
            w0.x = pk_bf16((a0.x - mu0) * rs0 * g0.x + d0.x, (a0.y - mu0) * rs0 * g0.y + d0.y);
            w0.y = pk_bf16((a0.z - mu0) * rs0 * g0.z + d0.z, (a0.w - mu0) * rs0 * g0.w + d0.w);
            w0.z = pk_bf16((a1.x - mu0) * rs0 * g1.x + d1.x, (a1.y - mu0) * rs0 * g1.y + d1.y);
            w0.w = pk_bf16((a1.z - mu0) * rs0 * g1.z + d1.z, (a1.w - mu0) * rs0 * g1.w + d1.w);
            w1.x = pk_bf16((c0.x - mu1) * rs1 * g0.x + d0.x, (c0.y - mu1) * rs1 * g0.y + d0.y);
            w1.y = pk_bf16((c0.z - mu1) * rs1 * g0.z + d0.z, (c0.w - mu1) * rs1 * g0.w + d0.w);
            w1.z = pk_bf16((c1.x - mu1) * rs1 * g1.x + d1.x, (c1.y - mu1) * rs1 * g1.y + d1.y);
            w1.w = pk_bf16((c1.z - mu1) * rs1 * g1.z + d1.z, (c1.w - mu1) * rs1 * g1.w + d1.w);
            *(uint4*)lA0 = w0;
            *(uint4*)lA1 = w1;
            __syncthreads();
#pragma unroll
            for (int kh = 0; kh < 2; ++kh) {
                bf16x8 af[2], bf[2];
#pragma unroll
                for (int mt = 0; mt < 2; ++mt) {
                    const int m = wm * 32 + mt * 16 + lq;
                    af[mt] = *(const bf16x8*)(As + m * 64 + (((lg + 4 * kh) ^ (m & 7)) << 3));
                }
#pragma unroll
                for (int nt = 0; nt < 2; ++nt) {
                    const int n = wn * 32 + nt * 16 + lq;
                    bf[nt] = *(const bf16x8*)(Bs + n * 64 + (((lg + 4 * kh) ^ (n & 7)) << 3));
                }
#pragma unroll
                for (int mt = 0; mt < 2; ++mt)
#pragma unroll
                    for (int nt = 0; nt < 2; ++nt)
                        acc[mt][nt] = __builtin_amdgcn_mfma_f32_16x16x32_bf16(af[mt], bf[nt], acc[mt][nt], 0, 0, 0);
            }
            __syncthreads();
        }

#pragma unroll
        for (int nt = 0; nt < 2; ++nt) {
            const int n = bn + wn * 32 + nt * 16 + lq;
            const int h = n >> 5, d = n & 31;
            const float bias = bq[n];
#pragma unroll
            for (int mt = 0; mt < 2; ++mt) {
                const int m0   = bm + wm * 32 + mt * 16 + lg * 4;
                const int bidx = m0 >> 9;
                const int tok  = m0 & 511;
                const size_t base = (((size_t)(bidx * NH + h) << 9) + tok) * 32 + d;
#pragma unroll
                for (int r = 0; r < 4; ++r)
                    qb[base + (size_t)r * 32] = f2bf((acc[mt][nt][r] + bias) * oscale);
            }
        }
    }
}

// ---------------------------------------------------------------------------
// MFMA flash attention, fixed-baseline softmax, 64-KV iterations.
// TRAFFIC lever: all prior variants moved 512MB of K/V (16 q-tiles x 32MB)
// through the L2-miss/L3 path at a measured-constant ~9.6 TB/s => ~53us
// regardless of occupancy/ordering. Q-TILE IS NOW 64 ROWS (NQ=4 16-row
// fragments), halving K/V passes: 8 x 32MB = 256MB => ~27us floor.
// Softmax+PV restructured per kv32-block (z) to keep transient regs small;
// K double-buffer dropped (BW-bound regime, waves hide L2 latency).
// Grid 1024 = 32 bh x 8 qt64 x 4 KV-quarters (XCD-swizzled, bh-major).
// Wave w owns KV [quarter*2048 + w*512, +512) = 8 iterations. Partials
// (unnormalized O 64x32 f32 + l) per quarter; attn_combine merges 4.
// ---------------------------------------------------------------------------
#define NQ 4
__global__ __launch_bounds__(256, 3) void attn_mfma_kernel(
    const ushort* __restrict__ Qb,  // [B*H][LQ][32] bf16, pre-scaled by log2e/sqrt(32)
    const ushort* __restrict__ Kb,  // [B*H][LKV][32]
    const ushort* __restrict__ Vt,  // [B*H][32][LKV]
    float* __restrict__ Opart,      // [4][32][8][64q][32d] f32 partials
    float* __restrict__ lpart)      // [4][32][8][64q] f32 partials
{
    const int bid = blockIdx.x;
    const int xcd = bid & 7;
    const int u   = bid >> 3;                // 0..127, sequential within an XCD
    const int bhw = u >> 5;                  // 0..3  bh-within-XCD (MAJOR)
    const int r2  = u & 31;
    const int qt  = r2 >> 2;                 // 0..7 (q-tile of 64)
    const int quarter = r2 & 3;              // 0..3: KV quarter [q*2048, +2048)
    const int bh  = (bhw << 3) | xcd;        // bh pinned to one XCD
    const int t = threadIdx.x, w = t >> 6, lane = t & 63;
    const int lq = lane & 15, lg = lane >> 4;

    __shared__ __align__(16) float Ob[2 * 64 * 36];   // 18432 B combine scratch
    __shared__ float lbuf[4][64];

    // Q frags (B operand of QK): lane holds Q[q=n*16+lq][k=lg*8+j]
    bf16x8 qfrag[NQ];
    const size_t qbase = ((size_t)bh * LQ + qt * 64) * 32;
#pragma unroll
    for (int n = 0; n < NQ; ++n)
        qfrag[n] = *(const bf16x8*)(Qb + qbase + (size_t)(n * 16 + lq) * 32 + lg * 8);

    const int kv0 = quarter * 2048 + w * 512;
    const ushort* KpA = Kb + ((size_t)bh * LKV + kv0 + lq) * 32 + lg * 8;
    const ushort* VpA = Vt + ((size_t)bh * 32 + lq) * LKV + kv0 + lg * 8;

    f32x4 oacc[2][NQ] = {};        // [d-tile][q-tile]
    float l_part[NQ] = {};
    const f32x4 cM = {-SMAX, -SMAX, -SMAX, -SMAX};

    for (int kt = 0; kt < 512; kt += 64) {
        // K frags (A operand of QK: lane = K[kv=m*16+lq][k=lg*8+j])
        bf16x8 kc[4];
#pragma unroll
        for (int m = 0; m < 4; ++m)
            kc[m] = *(const bf16x8*)(KpA + (size_t)(kt + m * 16) * 32);
        // V frags (A operand of PV): V^T[d=dt*16+lq][kv=kt+z*32+lg*8+j]
        bf16x8 vc[2][2];
#pragma unroll
        for (int dt = 0; dt < 2; ++dt)
#pragma unroll
            for (int z = 0; z < 2; ++z)
                vc[dt][z] = *(const bf16x8*)(VpA + (size_t)(dt * 16) * LKV + kt + z * 32);

        // per kv32-block: QK (K=32 MFMA) -> exp2 -> permlane interleave -> PV
#pragma unroll
        for (int z = 0; z < 2; ++z) {
            f32x4 s2[2][NQ];
#pragma unroll
            for (int mm = 0; mm < 2; ++mm)
#pragma unroll
                for (int n = 0; n < NQ; ++n)
                    s2[mm][n] = __builtin_amdgcn_mfma_f32_16x16x32_bf16(kc[2 * z + mm], qfrag[n], cM, 0, 0, 0);

            bf16x8 pfz[NQ];
#pragma unroll
            for (int n = 0; n < NQ; ++n) {
                const float e0 = EXP2F(s2[0][n][0]);
                const float e1 = EXP2F(s2[0][n][1]);
                const float e2 = EXP2F(s2[0][n][2]);
                const float e3 = EXP2F(s2[0][n][3]);
                const float f0 = EXP2F(s2[1][n][0]);
                const float f1 = EXP2F(s2[1][n][1]);
                const float f2 = EXP2F(s2[1][n][2]);
                const float f3 = EXP2F(s2[1][n][3]);
                l_part[n] += ((e0 + e1) + (e2 + e3)) + ((f0 + f1) + (f2 + f3));
                unsigned int wa = pk_bf16(e0, e1);
                unsigned int wb = pk_bf16(e2, e3);
                unsigned int wc = pk_bf16(f0, f1);
                unsigned int wd = pk_bf16(f2, f3);
                interleave_swap(wa, wc, lane);   // wa=W0, wc=W2
                interleave_swap(wb, wd, lane);   // wb=W1, wd=W3
                uint4 wv;
                wv.x = wa; wv.y = wb; wv.z = wc; wv.w = wd;
                pfz[n] = __builtin_bit_cast(bf16x8, wv);
            }

#pragma unroll
            for (int dt = 0; dt < 2; ++dt)
#pragma unroll
                for (int n = 0; n < NQ; ++n)
                    oacc[dt][n] = __builtin_amdgcn_mfma_f32_16x16x32_bf16(vc[dt][z], pfz[n], oacc[dt][n], 0, 0, 0);
        }
    }

    // ---- l reduce + 4-wave combine -> partial write ----
#pragma unroll
    for (int n = 0; n < NQ; ++n) {
        l_part[n] += __shfl_xor(l_part[n], 16);
        l_part[n] += __shfl_xor(l_part[n], 32);
    }
    if (lg == 0) {
#pragma unroll
        for (int n = 0; n < NQ; ++n)
            lbuf[w][n * 16 + lq] = l_part[n];
    }
    if (w >= 2) {
#pragma unroll
        for (int n = 0; n < NQ; ++n)
#pragma unroll
            for (int dt = 0; dt < 2; ++dt)
                *(f32x4*)&Ob[((size_t)(w - 2) * 64 + n * 16 + lq) * 36 + dt * 16 + lg * 4] = oacc[dt][n];
    }
    __syncthreads();
    if (w < 2) {
#pragma unroll
        for (int n = 0; n < NQ; ++n)
#pragma unroll
            for (int dt = 0; dt < 2; ++dt) {
                float* p = &Ob[((size_t)w * 64 + n * 16 + lq) * 36 + dt * 16 + lg * 4];
                f32x4 v = *(f32x4*)p;
                v += oacc[dt][n];
                *(f32x4*)p = v;
            }
    }
    __syncthreads();
    {
        const int pidx = (quarter * 32 + bh) * 8 + qt;
        const int q  = t >> 3;           // 0..31
        const int d0 = (t & 7) * 4;      // 0..28
#pragma unroll
        for (int rh = 0; rh < 2; ++rh) {
            const int row = q + rh * 32;
            f32x4 s0 = *(const f32x4*)&Ob[((size_t)row) * 36 + d0];
            f32x4 s1 = *(const f32x4*)&Ob[((size_t)(64 + row)) * 36 + d0];
            s0 += s1;
            *(f32x4*)(Opart + (size_t)pidx * 2048 + row * 32 + d0) = s0;
            if ((t & 7) == 0) {
                float gl = lbuf[0][row] + lbuf[1][row] + lbuf[2][row] + lbuf[3][row];
                lpart[(size_t)pidx * 64 + row] = gl;
            }
        }
    }
}

// ---------------------------------------------------------------------------
// Combine the 4 KV-quarter partials: Out = sum(Oq)/sum(lq). Grid 256 =
// bh*8+qt, 256 thr, 2 x float4 per thread.
// ---------------------------------------------------------------------------
__global__ __launch_bounds__(256) void attn_combine_kernel(
    const float* __restrict__ Opart, const float* __restrict__ lpart,
    float* __restrict__ Out)
{
    const int cb = blockIdx.x;               // 0..255
    const int bh = cb >> 3, qt = cb & 7;
    const int b = bh >> 3, h = bh & 7;
    const int t = threadIdx.x;
    const int q = t >> 3;                    // 0..31
    const int dq = (t & 7) * 4;              // 0..28
#pragma unroll
    for (int rh = 0; rh < 2; ++rh) {
        const int row = q + rh * 32;
        float4 o = {0.f, 0.f, 0.f, 0.f};
        float l = 0.f;
#pragma unroll
        for (int j = 0; j < 4; ++j) {
            const size_t pidx = (size_t)((j * 32 + bh) * 8 + qt);
            const float4 a = *(const float4*)(Opart + pidx * 2048 + row * 32 + dq);
            o.x += a.x; o.y += a.y; o.z += a.z; o.w += a.w;
            l += lpart[pidx * 64 + row];
        }
        const float inv = 1.0f / l;
        o.x *= inv; o.y *= inv; o.z *= inv; o.w *= inv;
        *(float4*)(Out + ((size_t)b * LQ + qt * 64 + row) * 256 + h * 32 + dq) = o;
    }
}

// ---------------------------------------------------------------------------
extern "C" void kernel_launch(void* const* d_in, const int* in_sizes, int n_in,
                              void* d_out, int out_size, void* d_ws, size_t ws_size,
                              hipStream_t stream)
{
    const float* hidden = (const float*)d_in[0];
    const float* inputs = (const float*)d_in[1];
    const float* ln1g   = (const float*)d_in[2];
    const float* ln1b   = (const float*)d_in[3];
    const float* ln2g   = (const float*)d_in[4];
    const float* ln2b   = (const float*)d_in[5];
    const float* Wq     = (const float*)d_in[6];
    const float* bq     = (const float*)d_in[7];
    const float* Wk     = (const float*)d_in[8];
    const float* bk     = (const float*)d_in[9];
    const float* Wv     = (const float*)d_in[10];
    const float* bv     = (const float*)d_in[11];
    float* out = (float*)d_out;

    // workspace (bytes), total ~66 MB
    char* wsb = (char*)d_ws;
    ushort* qb     = (ushort*)(wsb);                               // 1 MB   [32][512][32]
    ushort* WtKV   = (ushort*)(wsb + (1u << 20));                  // 0.5 MB [512][512]
    ushort* WtQ    = (ushort*)(wsb + (1u << 20) + (512u << 10));   // 0.5 MB [256][1024]
    float*  mean_h = (float*)(wsb + (2u << 20));                   // 8 KB
    float*  rstd_h = (float*)(wsb + (2u << 20) + 8192);            // 8 KB
    ushort* kb     = (ushort*)(wsb + (2u << 20) + 16384);          // 16 MB  [32][8192][32]
    ushort* vt     = (ushort*)(wsb + (18u << 20) + 16384);         // 16 MB  [32][32][8192]
    ushort* Abf    = (ushort*)(wsb + (34u << 20) + 16384);         // 32 MB  [32768][512]

    // Attention partials alias Abf (dead after phaseB): 8 MB + 256 KB << 32 MB
    float* Opart = (float*)Abf;                        // [4][32][8][64][32] f32
    float* lpart = Opart + (size_t)4 * 32 * 8 * 2048;  // [4][32][8][64] f32

    const float oscale = 0.2550540226496112f;   // log2(e)/sqrt(32): log2-domain softmax

    phaseA_kernel<<<8832, 256, 0, stream>>>(inputs, ln2g, ln2b, Abf,
                                            hidden, mean_h, rstd_h,
                                            Wq, Wk, Wv, WtQ, WtKV);
    phaseB_kernel<<<1152, 256, 0, stream>>>(Abf, WtKV, bk, bv, kb, vt,
                                            hidden, mean_h, rstd_h, ln1g, ln1b,
                                            WtQ, bq, qb, oscale);
    attn_mfma_kernel<<<1024, 256, 0, stream>>>(qb, kb, vt, Opart, lpart);
    attn_combine_kernel<<<256, 256, 0, stream>>>(Opart, lpart, out);
}

// Round 8
// 205.612 us; speedup vs baseline: 1.0650x; 1.0085x over previous
//
#include <hip/hip_runtime.h>
#include <hip/hip_bf16.h>
#include <math.h>

// Problem constants
#define NB    4
#define LQ    512
#define LKV   8192
#define QDIM  1024
#define KVDIM 512
#define NH    8
#define EPS_LN 1e-5f
#define SMAX  12.0f     // fixed softmax baseline (log2 domain); scores*log2e max ~9

typedef __attribute__((ext_vector_type(8))) short bf16x8;
typedef __attribute__((ext_vector_type(4))) float f32x4;

static __device__ __forceinline__ ushort f2bf(float x) {
    unsigned int u = __builtin_bit_cast(unsigned int, x);
    u += 0x7FFFu + ((u >> 16) & 1u);          // round-to-nearest-even
    return (ushort)(u >> 16);
}

#if __has_builtin(__builtin_amdgcn_cvt_pk_bf16_f32)
static __device__ __forceinline__ unsigned int pk_bf16(float a, float b) {
    auto r = __builtin_amdgcn_cvt_pk_bf16_f32(a, b);
    return __builtin_bit_cast(unsigned int, r);
}
#else
static __device__ __forceinline__ unsigned int pk_bf16(float a, float b) {
    return (unsigned int)f2bf(a) | ((unsigned int)f2bf(b) << 16);
}
#endif

#if __has_builtin(__builtin_amdgcn_exp2f)
#define EXP2F(x) __builtin_amdgcn_exp2f(x)
#else
#define EXP2F(x) exp2f(x)
#endif

// In-register 4-row interleave across 16-lane groups:
//   x in rows [a0,a1,a2,a3], y in rows [b0,b1,b2,b3]  (rows = 16-lane groups)
//   -> x = [a0,a2,b0,b2], y = [a1,a3,b1,b3]
// Used to convert the MFMA C/D row grouping (lg*4+r) into the K=32 B-operand
// grouping (lg*8+j) without touching LDS. permlane*_swap are full-rate VALU.
static __device__ __forceinline__ void interleave_swap(unsigned int &x, unsigned int &y, int lane) {
#if __has_builtin(__builtin_amdgcn_permlane32_swap) && __has_builtin(__builtin_amdgcn_permlane16_swap)
    {
        auto r1 = __builtin_amdgcn_permlane32_swap(x, y, false, false);
        auto r2 = __builtin_amdgcn_permlane16_swap(r1[0], r1[1], false, false);
        x = (unsigned int)r2[0];
        y = (unsigned int)r2[1];
    }
#else
    {
        // pl32swap: A2={x.r0,x.r1,y.r0,y.r1}, C2={x.r2,x.r3,y.r2,y.r3}
        unsigned int xs = (unsigned int)__shfl_xor((int)x, 32, 64);
        unsigned int ys = (unsigned int)__shfl_xor((int)y, 32, 64);
        unsigned int A2 = (lane & 32) ? ys : x;
        unsigned int C2 = (lane & 32) ? y  : xs;
        // pl16swap: x'={A2.r0,C2.r0,A2.r2,C2.r2}, y'={A2.r1,C2.r1,A2.r3,C2.r3}
        unsigned int A2x = (unsigned int)__shfl_xor((int)A2, 16, 64);
        unsigned int C2x = (unsigned int)__shfl_xor((int)C2, 16, 64);
        x = (lane & 16) ? C2x : A2;
        y = (lane & 16) ? C2  : A2x;
    }
#endif
}

// async global->LDS, 16B per lane; LDS dest = wave base + lane*16
static __device__ __forceinline__ void gld_lds16(const ushort* g, ushort* l) {
    __builtin_amdgcn_global_load_lds(
        (const __attribute__((address_space(1))) unsigned int*)g,
        (__attribute__((address_space(3))) unsigned int*)l, 16, 0, 0);
}

// ---------------------------------------------------------------------------
// LN normalize one row -> bf16 (wave per row).
// ---------------------------------------------------------------------------
template<int K>
static __device__ __forceinline__ void ln_norm_row(
    const float* __restrict__ x, const float* __restrict__ g,
    const float* __restrict__ bta, ushort* __restrict__ y, int row, int lane)
{
    const float* xp = x + (size_t)row * K;
    constexpr int NV = K / 256;
    float4 v[NV];
    float s = 0.f;
#pragma unroll
    for (int i = 0; i < NV; ++i) {
        v[i] = *(const float4*)(xp + lane * 4 + i * 256);
        s += v[i].x + v[i].y + v[i].z + v[i].w;
    }
#pragma unroll
    for (int o = 1; o < 64; o <<= 1) s += __shfl_xor(s, o, 64);
    const float mu = s * (1.0f / K);
    float vs = 0.f;
#pragma unroll
    for (int i = 0; i < NV; ++i) {
        float dx = v[i].x - mu, dy = v[i].y - mu, dz = v[i].z - mu, dw = v[i].w - mu;
        vs += dx * dx + dy * dy + dz * dz + dw * dw;
    }
#pragma unroll
    for (int o = 1; o < 64; o <<= 1) vs += __shfl_xor(vs, o, 64);
    const float rs = rsqrtf(vs * (1.0f / K) + EPS_LN);
#pragma unroll
    for (int i = 0; i < NV; ++i) {
        const float4 gv = *(const float4*)(g   + lane * 4 + i * 256);
        const float4 bv = *(const float4*)(bta + lane * 4 + i * 256);
        uint2 o;
        o.x = pk_bf16((v[i].x - mu) * rs * gv.x + bv.x, (v[i].y - mu) * rs * gv.y + bv.y);
        o.y = pk_bf16((v[i].z - mu) * rs * gv.z + bv.z, (v[i].w - mu) * rs * gv.w + bv.w);
        *(uint2*)(y + (size_t)row * K + lane * 4 + i * 256) = o;
    }
}

// LN stats only (K=1024), wave per row.
static __device__ __forceinline__ void ln_stats_row(
    const float* __restrict__ x, float* __restrict__ mean, float* __restrict__ rstd,
    int row, int lane)
{
    const float* xp = x + (size_t)row * QDIM;
    float4 v[4];
    float s = 0.f;
#pragma unroll
    for (int i = 0; i < 4; ++i) {
        v[i] = *(const float4*)(xp + lane * 4 + i * 256);
        s += v[i].x + v[i].y + v[i].z + v[i].w;
    }
#pragma unroll
    for (int o = 1; o < 64; o <<= 1) s += __shfl_xor(s, o, 64);
    const float mu = s * (1.0f / QDIM);
    float vs = 0.f;
#pragma unroll
    for (int i = 0; i < 4; ++i) {
        float dx = v[i].x - mu, dy = v[i].y - mu, dz = v[i].z - mu, dw = v[i].w - mu;
        vs += dx * dx + dy * dy + dz * dz + dw * dw;
    }
#pragma unroll
    for (int o = 1; o < 64; o <<= 1) vs += __shfl_xor(vs, o, 64);
    if (lane == 0) {
        mean[row] = mu;
        rstd[row] = rsqrtf(vs * (1.0f / QDIM) + EPS_LN);
    }
}

// 64x64 transpose tile: dst[n][k] = bf16(src[k][n]), src is [K][256].
static __device__ __forceinline__ void wt_transpose_body(
    const float* __restrict__ src, ushort* __restrict__ dst, int K,
    int kx, int ny, int t, ushort (*Ts)[72])
{
    const int k0 = kx * 64, n0 = ny * 64;
    const int nl = t & 63;
#pragma unroll
    for (int p = 0; p < 16; ++p) {
        const int kl = p * 4 + (t >> 6);
        Ts[nl][kl] = f2bf(src[(size_t)(k0 + kl) * 256 + n0 + nl]);
    }
    __syncthreads();
    const int ck = (t & 7) * 8;
#pragma unroll
    for (int p = 0; p < 2; ++p) {
        const int rn = p * 32 + (t >> 3);
        *(bf16x8*)(dst + (size_t)(n0 + rn) * K + k0 + ck) = *(const bf16x8*)&Ts[rn][ck];
    }
}

// ---------------------------------------------------------------------------
// Phase A (one launch): KV normalize (8192 blk) + Q LN stats (512 blk)
// + Wq/Wk/Wv transposes (64+32+32 blk). 256 threads.
// ---------------------------------------------------------------------------
__global__ __launch_bounds__(256) void phaseA_kernel(
    const float* __restrict__ inputs, const float* __restrict__ ln2g,
    const float* __restrict__ ln2b,   ushort* __restrict__ Abf,
    const float* __restrict__ hidden, float* __restrict__ mean_h, float* __restrict__ rstd_h,
    const float* __restrict__ Wq, const float* __restrict__ Wk, const float* __restrict__ Wv,
    ushort* __restrict__ WtQ, ushort* __restrict__ WtKV)
{
    __shared__ ushort Ts[64][72];
    const int bid = blockIdx.x;
    const int t = threadIdx.x;
    const int lane = t & 63;
    if (bid < 8192) {
        ln_norm_row<KVDIM>(inputs, ln2g, ln2b, Abf, bid * 4 + (t >> 6), lane);
    } else if (bid < 8704) {
        ln_stats_row(hidden, mean_h, rstd_h, (bid - 8192) * 4 + (t >> 6), lane);
    } else if (bid < 8768) {
        const int p = bid - 8704;
        wt_transpose_body(Wq, WtQ, QDIM, p & 15, p >> 4, t, Ts);
    } else if (bid < 8800) {
        const int p = bid - 8768;
        wt_transpose_body(Wk, WtKV, KVDIM, p & 7, p >> 3, t, Ts);
    } else {
        const int p = bid - 8800;
        wt_transpose_body(Wv, WtKV + (size_t)256 * KVDIM, KVDIM, p & 7, p >> 3, t, Ts);
    }
}

// ---------------------------------------------------------------------------
// Phase B (one launch, 256 thr): blocks [0,2048) = KV GEMM (64x128, BK=64),
// blocks [2048,2176) = Q GEMM (64x64, BK=64, LN fused into A staging).
// KV GEMM retiled 128x128 -> 64x128: grid 1024->2048 (8 blk/CU of work),
// acc 64->32 AGPR/wave (wave owns 64 rows x 32 cols = one head's columns),
// staging 24KB/step -> ~3 blocks/CU co-resident (the m114 overlap that the
// old 1-block/CU config lacked; phaseB was latency-bound at Occ=13.5%).
// bid XCD-chunked so the 4 bn-siblings of an A-tile share one XCD's L2.
// ---------------------------------------------------------------------------
__global__ __launch_bounds__(256, 3) void phaseB_kernel(
    const ushort* __restrict__ Abf, const ushort* __restrict__ WtKV,
    const float* __restrict__ bk, const float* __restrict__ bv,
    ushort* __restrict__ kb, ushort* __restrict__ vt,
    const float* __restrict__ hidden, const float* __restrict__ mean_h,
    const float* __restrict__ rstd_h,
    const float* __restrict__ ln1g, const float* __restrict__ ln1b,
    const ushort* __restrict__ WtQ, const float* __restrict__ bq,
    ushort* __restrict__ qb, float oscale)
{
    __shared__ __align__(16) ushort SMEM[4 * 64 * 72];   // 36864 B
    const int bid  = blockIdx.x;
    const int t    = threadIdx.x;
    const int lane = t & 63;
    const int w    = t >> 6;
    const int lq   = lane & 15;
    const int lg   = lane >> 4;
    const int wm   = w >> 1;
    const int wn   = w & 1;

    if (bid < 2048) {
        // ================= KV GEMM (64x128 tile, BK=64) =================
        const int work = ((bid & 7) << 8) | (bid >> 3);   // XCD-chunked swizzle
        const int bm = (work >> 2) * 64;
        const int bn = (work & 3) * 128;
        ushort* As = SMEM;            // [64][64] swizzled, 4096 ushorts
        ushort* Bs = SMEM + 4096;     // [128][64] swizzled, 8192 ushorts

        const int srow = t >> 3;                              // 0..31
        const int scol = ((t & 7) ^ (srow & 7)) * 8;          // xor-swizzled col
        const ushort* gA = Abf  + (size_t)(bm + srow) * KVDIM + scol;
        const ushort* gB = WtKV + (size_t)(bn + srow) * KVDIM + scol;

        f32x4 acc[4][2] = {};        // wave: rows [0,64) x cols [w*32, +32)
        for (int k0 = 0; k0 < KVDIM; k0 += 64) {
            gld_lds16(gA + k0,                      As + t * 8);
            gld_lds16(gA + (size_t)32 * KVDIM + k0, As + 2048 + t * 8);
#pragma unroll
            for (int p = 0; p < 4; ++p)
                gld_lds16(gB + (size_t)(p * 32) * KVDIM + k0, Bs + p * 2048 + t * 8);
            __syncthreads();
#pragma unroll
            for (int kh = 0; kh < 2; ++kh) {
                bf16x8 af[4], bf[2];
#pragma unroll
                for (int mt = 0; mt < 4; ++mt) {
                    const int m = mt * 16 + lq;
                    af[mt] = *(const bf16x8*)(As + m * 64 + (((lg + 4 * kh) ^ (m & 7)) << 3));
                }
#pragma unroll
                for (int nt = 0; nt < 2; ++nt) {
                    const int n = w * 32 + nt * 16 + lq;
                    bf[nt] = *(const bf16x8*)(Bs + n * 64 + (((lg + 4 * kh) ^ (n & 7)) << 3));
                }
#pragma unroll
                for (int mt = 0; mt < 4; ++mt)
#pragma unroll
                    for (int nt = 0; nt < 2; ++nt)
                        acc[mt][nt] = __builtin_amdgcn_mfma_f32_16x16x32_bf16(af[mt], bf[nt], acc[mt][nt], 0, 0, 0);
            }
            __syncthreads();
        }
        // Post-loop: per-wave epilogue scratch (SMEM + w*2560), no cross-wave use.
        const int bidx = bm >> 13;
        const int tokb = bm & 8191;
        const int nc0  = bn + w * 32;          // wave's output-col base (mult of 32)

        if (bn < 256) {
            // ---- K path: Cs[tok 64][col 32] (stride 40) -> 16B row stores ----
            ushort* Cs = SMEM + w * 2560;
#pragma unroll
            for (int nt = 0; nt < 2; ++nt) {
                const int n_l = nt * 16 + lq;
                const float bias = bk[nc0 + n_l];
#pragma unroll
                for (int mt = 0; mt < 4; ++mt)
#pragma unroll
                    for (int r = 0; r < 4; ++r)
                        Cs[(mt * 16 + lg * 4 + r) * 40 + n_l] = f2bf(acc[mt][nt][r] + bias);
            }
            const int r0 = lane >> 2;          // 0..15
            const int ck = (lane & 3) * 8;     // 0..24
            const int h  = nc0 >> 5;           // one head per wave
            const size_t obase = (((size_t)(bidx * NH + h) << 13) + tokb) * 32 + ck;
#pragma unroll
            for (int p = 0; p < 4; ++p) {
                const int row = p * 16 + r0;
                *(bf16x8*)(kb + obase + (size_t)row * 32) = *(const bf16x8*)&Cs[row * 40 + ck];
            }
        } else {
            // ---- V path: Cs[col 32][tok 64] (stride 72) -> vT 16B stores ----
            ushort* Cs = SMEM + w * 2560;
#pragma unroll
            for (int nt = 0; nt < 2; ++nt) {
                const int n_l = nt * 16 + lq;
                const float bias = bv[(nc0 - 256) + n_l];
#pragma unroll
                for (int mt = 0; mt < 4; ++mt) {
                    uint2 o;
                    o.x = pk_bf16(acc[mt][nt][0] + bias, acc[mt][nt][1] + bias);
                    o.y = pk_bf16(acc[mt][nt][2] + bias, acc[mt][nt][3] + bias);
                    *(uint2*)&Cs[n_l * 72 + mt * 16 + lg * 4] = o;
                }
            }
            const int r0 = lane >> 3;          // 0..7
            const int cm = (lane & 7) * 8;     // 0..56
            const int nv0 = nc0 - 256;
            const int h  = nv0 >> 5;           // one head per wave
            const int tokc = tokb + cm;
#pragma unroll
            for (int p = 0; p < 4; ++p) {
                const int row = p * 8 + r0;    // 0..31 = d within head
                *(bf16x8*)(vt + ((size_t)(bidx * NH + h) * 32 + row) * LKV + tokc) =
                    *(const bf16x8*)&Cs[row * 72 + cm];
            }
        }
    } else {
        // ================= Q GEMM (LN fused) =================
        const int p  = bid - 2048;
        const int bm = (p >> 2) * 64;
        const int bn = (p & 3) * 64;
        ushort* As = SMEM;
        ushort* Bs = SMEM + 4096;

        const int srow = t >> 3;                              // 0..31
        const int scol = ((t & 7) ^ (srow & 7)) * 8;          // xor-swizzled col
        const ushort* gB = WtQ + (size_t)(bn + srow) * QDIM + scol;
        ushort* lB  = Bs + t * 8;
        ushort* lA0 = As + t * 8;
        ushort* lA1 = As + 2048 + t * 8;

        const int r0 = bm + srow;
        const float mu0 = mean_h[r0],      rs0 = rstd_h[r0];
        const float mu1 = mean_h[r0 + 32], rs1 = rstd_h[r0 + 32];
        const float* xA0 = hidden + (size_t)r0 * QDIM + scol;
        const float* xA1 = xA0 + (size_t)32 * QDIM;

        f32x4 acc[2][2] = {};
        for (int k0 = 0; k0 < QDIM; k0 += 64) {
            gld_lds16(gB + k0,                      lB);
            gld_lds16(gB + (size_t)32 * QDIM + k0,  lB + 2048);
            const float4 a0 = *(const float4*)(xA0 + k0);
            const float4 a1 = *(const float4*)(xA0 + k0 + 4);
            const float4 c0 = *(const float4*)(xA1 + k0);
            const float4 c1 = *(const float4*)(xA1 + k0 + 4);
            const float4 g0 = *(const float4*)(ln1g + k0 + scol);
            const float4 g1 = *(const float4*)(ln1g + k0 + scol + 4);
            const float4 d0 = *(const float4*)(ln1b + k0 + scol);
            const float4 d1 = *(const float4*)(ln1b + k0 + scol + 4);
            uint4 w0, w1;
            w0.x = pk_bf16((a0.x - mu0) * rs0 * g0.x + d0.x, (a0.y - mu0) * rs0 * g0.y + d0.y);
            w0.y = pk_bf16((a0.z - mu0) * rs0 * g0.z + d0.z, (a0.w - mu0) * rs0 * g0.w + d0.w);
            w0.z = pk_bf16((a1.x - mu0) * rs0 * g1.x + d1.x, (a1.y - mu0) * rs0 * g1.y + d1.y);
            w0.w = pk_bf16((a1.z - mu0) * rs0 * g1.z + d1.z, (a1.w - mu0) * rs0 * g1.w + d1.w);
            w1.x = pk_bf16((c0.x - mu1) * rs1 * g0.x + d0.x, (c0.y - mu1) * rs1 * g0.y + d0.y);
            w1.y = pk_bf16((c0.z - mu1) * rs1 * g0.z + d0.z, (c0.w - mu1) * rs1 * g0.w + d0.w);
            w1.z = pk_bf16((c1.x - mu1) * rs1 * g1.x + d1.x, (c1.y - mu1) * rs1 * g1.y + d1.y);
            w1.w = pk_bf16((c1.z - mu1) * rs1 * g1.z + d1.z, (c1.w - mu1) * rs1 * g1.w + d1.w);
            *(uint4*)lA0 = w0;
            *(uint4*)lA1 = w1;
            __syncthreads();
#pragma unroll
            for (int kh = 0; kh < 2; ++kh) {
                bf16x8 af[2], bf[2];
#pragma unroll
                for (int mt = 0; mt < 2; ++mt) {
                    const int m = wm * 32 + mt * 16 + lq;
                    af[mt] = *(const bf16x8*)(As + m * 64 + (((lg + 4 * kh) ^ (m & 7)) << 3));
                }
#pragma unroll
                for (int nt = 0; nt < 2; ++nt) {
                    const int n = wn * 32 + nt * 16 + lq;
                    bf[nt] = *(const bf16x8*)(Bs + n * 64 + (((lg + 4 * kh) ^ (n & 7)) << 3));
                }
#pragma unroll
                for (int mt = 0; mt < 2; ++mt)
#pragma unroll
                    for (int nt = 0; nt < 2; ++nt)
                        acc[mt][nt] = __builtin_amdgcn_mfma_f32_16x16x32_bf16(af[mt], bf[nt], acc[mt][nt], 0, 0, 0);
            }
            __syncthreads();
        }

#pragma unroll
        for (int nt = 0; nt < 2; ++nt) {
            const int n = bn + wn * 32 + nt * 16 + lq;
            const int h = n >> 5, d = n & 31;
            const float bias = bq[n];
#pragma unroll
            for (int mt = 0; mt < 2; ++mt) {
                const int m0   = bm + wm * 32 + mt * 16 + lg * 4;
                const int bidx = m0 >> 9;
                const int tok  = m0 & 511;
                const size_t base = (((size_t)(bidx * NH + h) << 9) + tok) * 32 + d;
#pragma unroll
                for (int r = 0; r < 4; ++r)
                    qb[base + (size_t)r * 32] = f2bf((acc[mt][nt][r] + bias) * oscale);
            }
        }
    }
}

// ---------------------------------------------------------------------------
// MFMA flash attention, fixed-baseline softmax, 64-KV iterations.
// Q-tile 64 rows (NQ=4), KV quarters, partials merged by attn_combine.
// (unchanged from round 7 — traffic-limited at ~256MB through L2-miss path)
// ---------------------------------------------------------------------------
#define NQ 4
__global__ __launch_bounds__(256, 3) void attn_mfma_kernel(
    const ushort* __restrict__ Qb,  // [B*H][LQ][32] bf16, pre-scaled by log2e/sqrt(32)
    const ushort* __restrict__ Kb,  // [B*H][LKV][32]
    const ushort* __restrict__ Vt,  // [B*H][32][LKV]
    float* __restrict__ Opart,      // [4][32][8][64q][32d] f32 partials
    float* __restrict__ lpart)      // [4][32][8][64q] f32 partials
{
    const int bid = blockIdx.x;
    const int xcd = bid & 7;
    const int u   = bid >> 3;                // 0..127, sequential within an XCD
    const int bhw = u >> 5;                  // 0..3  bh-within-XCD (MAJOR)
    const int r2  = u & 31;
    const int qt  = r2 >> 2;                 // 0..7 (q-tile of 64)
    const int quarter = r2 & 3;              // 0..3: KV quarter [q*2048, +2048)
    const int bh  = (bhw << 3) | xcd;        // bh pinned to one XCD
    const int t = threadIdx.x, w = t >> 6, lane = t & 63;
    const int lq = lane & 15, lg = lane >> 4;

    __shared__ __align__(16) float Ob[2 * 64 * 36];   // 18432 B combine scratch
    __shared__ float lbuf[4][64];

    // Q frags (B operand of QK): lane holds Q[q=n*16+lq][k=lg*8+j]
    bf16x8 qfrag[NQ];
    const size_t qbase = ((size_t)bh * LQ + qt * 64) * 32;
#pragma unroll
    for (int n = 0; n < NQ; ++n)
        qfrag[n] = *(const bf16x8*)(Qb + qbase + (size_t)(n * 16 + lq) * 32 + lg * 8);

    const int kv0 = quarter * 2048 + w * 512;
    const ushort* KpA = Kb + ((size_t)bh * LKV + kv0 + lq) * 32 + lg * 8;
    const ushort* VpA = Vt + ((size_t)bh * 32 + lq) * LKV + kv0 + lg * 8;

    f32x4 oacc[2][NQ] = {};        // [d-tile][q-tile]
    float l_part[NQ] = {};
    const f32x4 cM = {-SMAX, -SMAX, -SMAX, -SMAX};

    for (int kt = 0; kt < 512; kt += 64) {
        // K frags (A operand of QK: lane = K[kv=m*16+lq][k=lg*8+j])
        bf16x8 kc[4];
#pragma unroll
        for (int m = 0; m < 4; ++m)
            kc[m] = *(const bf16x8*)(KpA + (size_t)(kt + m * 16) * 32);
        // V frags (A operand of PV): V^T[d=dt*16+lq][kv=kt+z*32+lg*8+j]
        bf16x8 vc[2][2];
#pragma unroll
        for (int dt = 0; dt < 2; ++dt)
#pragma unroll
            for (int z = 0; z < 2; ++z)
                vc[dt][z] = *(const bf16x8*)(VpA + (size_t)(dt * 16) * LKV + kt + z * 32);

        // per kv32-block: QK (K=32 MFMA) -> exp2 -> permlane interleave -> PV
#pragma unroll
        for (int z = 0; z < 2; ++z) {
            f32x4 s2[2][NQ];
#pragma unroll
            for (int mm = 0; mm < 2; ++mm)
#pragma unroll
                for (int n = 0; n < NQ; ++n)
                    s2[mm][n] = __builtin_amdgcn_mfma_f32_16x16x32_bf16(kc[2 * z + mm], qfrag[n], cM, 0, 0, 0);

            bf16x8 pfz[NQ];
#pragma unroll
            for (int n = 0; n < NQ; ++n) {
                const float e0 = EXP2F(s2[0][n][0]);
                const float e1 = EXP2F(s2[0][n][1]);
                const float e2 = EXP2F(s2[0][n][2]);
                const float e3 = EXP2F(s2[0][n][3]);
                const float f0 = EXP2F(s2[1][n][0]);
                const float f1 = EXP2F(s2[1][n][1]);
                const float f2 = EXP2F(s2[1][n][2]);
                const float f3 = EXP2F(s2[1][n][3]);
                l_part[n] += ((e0 + e1) + (e2 + e3)) + ((f0 + f1) + (f2 + f3));
                unsigned int wa = pk_bf16(e0, e1);
                unsigned int wb = pk_bf16(e2, e3);
                unsigned int wc = pk_bf16(f0, f1);
                unsigned int wd = pk_bf16(f2, f3);
                interleave_swap(wa, wc, lane);   // wa=W0, wc=W2
                interleave_swap(wb, wd, lane);   // wb=W1, wd=W3
                uint4 wv;
                wv.x = wa; wv.y = wb; wv.z = wc; wv.w = wd;
                pfz[n] = __builtin_bit_cast(bf16x8, wv);
            }

#pragma unroll
            for (int dt = 0; dt < 2; ++dt)
#pragma unroll
                for (int n = 0; n < NQ; ++n)
                    oacc[dt][n] = __builtin_amdgcn_mfma_f32_16x16x32_bf16(vc[dt][z], pfz[n], oacc[dt][n], 0, 0, 0);
        }
    }

    // ---- l reduce + 4-wave combine -> partial write ----
#pragma unroll
    for (int n = 0; n < NQ; ++n) {
        l_part[n] += __shfl_xor(l_part[n], 16);
        l_part[n] += __shfl_xor(l_part[n], 32);
    }
    if (lg == 0) {
#pragma unroll
        for (int n = 0; n < NQ; ++n)
            lbuf[w][n * 16 + lq] = l_part[n];
    }
    if (w >= 2) {
#pragma unroll
        for (int n = 0; n < NQ; ++n)
#pragma unroll
            for (int dt = 0; dt < 2; ++dt)
                *(f32x4*)&Ob[((size_t)(w - 2) * 64 + n * 16 + lq) * 36 + dt * 16 + lg * 4] = oacc[dt][n];
    }
    __syncthreads();
    if (w < 2) {
#pragma unroll
        for (int n = 0; n < NQ; ++n)
#pragma unroll
            for (int dt = 0; dt < 2; ++dt) {
                float* p = &Ob[((size_t)w * 64 + n * 16 + lq) * 36 + dt * 16 + lg * 4];
                f32x4 v = *(f32x4*)p;
                v += oacc[dt][n];
                *(f32x4*)p = v;
            }
    }
    __syncthreads();
    {
        const int pidx = (quarter * 32 + bh) * 8 + qt;
        const int q  = t >> 3;           // 0..31
        const int d0 = (t & 7) * 4;      // 0..28
#pragma unroll
        for (int rh = 0; rh < 2; ++rh) {
            const int row = q + rh * 32;
            f32x4 s0 = *(const f32x4*)&Ob[((size_t)row) * 36 + d0];
            f32x4 s1 = *(const f32x4*)&Ob[((size_t)(64 + row)) * 36 + d0];
            s0 += s1;
            *(f32x4*)(Opart + (size_t)pidx * 2048 + row * 32 + d0) = s0;
            if ((t & 7) == 0) {
                float gl = lbuf[0][row] + lbuf[1][row] + lbuf[2][row] + lbuf[3][row];
                lpart[(size_t)pidx * 64 + row] = gl;
            }
        }
    }
}

// ---------------------------------------------------------------------------
// Combine the 4 KV-quarter partials: Out = sum(Oq)/sum(lq). Grid 256 =
// bh*8+qt, 256 thr, 2 x float4 per thread.
// ---------------------------------------------------------------------------
__global__ __launch_bounds__(256) void attn_combine_kernel(
    const float* __restrict__ Opart, const float* __restrict__ lpart,
    float* __restrict__ Out)
{
    const int cb = blockIdx.x;               // 0..255
    const int bh = cb >> 3, qt = cb & 7;
    const int b = bh >> 3, h = bh & 7;
    const int t = threadIdx.x;
    const int q = t >> 3;                    // 0..31
    const int dq = (t & 7) * 4;              // 0..28
#pragma unroll
    for (int rh = 0; rh < 2; ++rh) {
        const int row = q + rh * 32;
        float4 o = {0.f, 0.f, 0.f, 0.f};
        float l = 0.f;
#pragma unroll
        for (int j = 0; j < 4; ++j) {
            const size_t pidx = (size_t)((j * 32 + bh) * 8 + qt);
            const float4 a = *(const float4*)(Opart + pidx * 2048 + row * 32 + dq);
            o.x += a.x; o.y += a.y; o.z += a.z; o.w += a.w;
            l += lpart[pidx * 64 + row];
        }
        const float inv = 1.0f / l;
        o.x *= inv; o.y *= inv; o.z *= inv; o.w *= inv;
        *(float4*)(Out + ((size_t)b * LQ + qt * 64 + row) * 256 + h * 32 + dq) = o;
    }
}

// ---------------------------------------------------------------------------
extern "C" void kernel_launch(void* const* d_in, const int* in_sizes, int n_in,
                              void* d_out, int out_size, void* d_ws, size_t ws_size,
                              hipStream_t stream)
{
    const float* hidden = (const float*)d_in[0];
    const float* inputs = (const float*)d_in[1];
    const float* ln1g   = (const float*)d_in[2];
    const float* ln1b   = (const float*)d_in[3];
    const float* ln2g   = (const float*)d_in[4];
    const float* ln2b   = (const float*)d_in[5];
    const float* Wq     = (const float*)d_in[6];
    const float* bq     = (const float*)d_in[7];
    const float* Wk     = (const float*)d_in[8];
    const float* bk     = (const float*)d_in[9];
    const float* Wv     = (const float*)d_in[10];
    const float* bv     = (const float*)d_in[11];
    float* out = (float*)d_out;

    // workspace (bytes), total ~66 MB
    char* wsb = (char*)d_ws;
    ushort* qb     = (ushort*)(wsb);                               // 1 MB   [32][512][32]
    ushort* WtKV   = (ushort*)(wsb + (1u << 20));                  // 0.5 MB [512][512]
    ushort* WtQ    = (ushort*)(wsb + (1u << 20) + (512u << 10));   // 0.5 MB [256][1024]
    float*  mean_h = (float*)(wsb + (2u << 20));                   // 8 KB
    float*  rstd_h = (float*)(wsb + (2u << 20) + 8192);            // 8 KB
    ushort* kb     = (ushort*)(wsb + (2u << 20) + 16384);          // 16 MB  [32][8192][32]
    ushort* vt     = (ushort*)(wsb + (18u << 20) + 16384);         // 16 MB  [32][32][8192]
    ushort* Abf    = (ushort*)(wsb + (34u << 20) + 16384);         // 32 MB  [32768][512]

    // Attention partials alias Abf (dead after phaseB): 8 MB + 256 KB << 32 MB
    float* Opart = (float*)Abf;                        // [4][32][8][64][32] f32
    float* lpart = Opart + (size_t)4 * 32 * 8 * 2048;  // [4][32][8][64] f32

    const float oscale = 0.2550540226496112f;   // log2(e)/sqrt(32): log2-domain softmax

    phaseA_kernel<<<8832, 256, 0, stream>>>(inputs, ln2g, ln2b, Abf,
                                            hidden, mean_h, rstd_h,
                                            Wq, Wk, Wv, WtQ, WtKV);
    phaseB_kernel<<<2176, 256, 0, stream>>>(Abf, WtKV, bk, bv, kb, vt,
                                            hidden, mean_h, rstd_h, ln1g, ln1b,
                                            WtQ, bq, qb, oscale);
    attn_mfma_kernel<<<1024, 256, 0, stream>>>(qb, kb, vt, Opart, lpart);
    attn_combine_kernel<<<256, 256, 0, stream>>>(Opart, lpart, out);
}

// Round 9
// 201.993 us; speedup vs baseline: 1.0841x; 1.0179x over previous
//
#include <hip/hip_runtime.h>
#include <hip/hip_bf16.h>
#include <math.h>

// Problem constants
#define NB    4
#define LQ    512
#define LKV   8192
#define QDIM  1024
#define KVDIM 512
#define NH    8
#define EPS_LN 1e-5f
#define SMAX  12.0f     // fixed softmax baseline (log2 domain); scores*log2e max ~9

typedef __attribute__((ext_vector_type(8))) short bf16x8;
typedef __attribute__((ext_vector_type(4))) float f32x4;

static __device__ __forceinline__ ushort f2bf(float x) {
    unsigned int u = __builtin_bit_cast(unsigned int, x);
    u += 0x7FFFu + ((u >> 16) & 1u);          // round-to-nearest-even
    return (ushort)(u >> 16);
}

#if __has_builtin(__builtin_amdgcn_cvt_pk_bf16_f32)
static __device__ __forceinline__ unsigned int pk_bf16(float a, float b) {
    auto r = __builtin_amdgcn_cvt_pk_bf16_f32(a, b);
    return __builtin_bit_cast(unsigned int, r);
}
#else
static __device__ __forceinline__ unsigned int pk_bf16(float a, float b) {
    return (unsigned int)f2bf(a) | ((unsigned int)f2bf(b) << 16);
}
#endif

#if __has_builtin(__builtin_amdgcn_exp2f)
#define EXP2F(x) __builtin_amdgcn_exp2f(x)
#else
#define EXP2F(x) exp2f(x)
#endif

// In-register 4-row interleave across 16-lane groups:
//   x in rows [a0,a1,a2,a3], y in rows [b0,b1,b2,b3]  (rows = 16-lane groups)
//   -> x = [a0,a2,b0,b2], y = [a1,a3,b1,b3]
// Used to convert the MFMA C/D row grouping (lg*4+r) into the K=32 B-operand
// grouping (lg*8+j) without touching LDS. permlane*_swap are full-rate VALU.
static __device__ __forceinline__ void interleave_swap(unsigned int &x, unsigned int &y, int lane) {
#if __has_builtin(__builtin_amdgcn_permlane32_swap) && __has_builtin(__builtin_amdgcn_permlane16_swap)
    {
        auto r1 = __builtin_amdgcn_permlane32_swap(x, y, false, false);
        auto r2 = __builtin_amdgcn_permlane16_swap(r1[0], r1[1], false, false);
        x = (unsigned int)r2[0];
        y = (unsigned int)r2[1];
    }
#else
    {
        // pl32swap: A2={x.r0,x.r1,y.r0,y.r1}, C2={x.r2,x.r3,y.r2,y.r3}
        unsigned int xs = (unsigned int)__shfl_xor((int)x, 32, 64);
        unsigned int ys = (unsigned int)__shfl_xor((int)y, 32, 64);
        unsigned int A2 = (lane & 32) ? ys : x;
        unsigned int C2 = (lane & 32) ? y  : xs;
        // pl16swap: x'={A2.r0,C2.r0,A2.r2,C2.r2}, y'={A2.r1,C2.r1,A2.r3,C2.r3}
        unsigned int A2x = (unsigned int)__shfl_xor((int)A2, 16, 64);
        unsigned int C2x = (unsigned int)__shfl_xor((int)C2, 16, 64);
        x = (lane & 16) ? C2x : A2;
        y = (lane & 16) ? C2  : A2x;
    }
#endif
}

// async global->LDS, 16B per lane; LDS dest = wave base + lane*16
static __device__ __forceinline__ void gld_lds16(const ushort* g, ushort* l) {
    __builtin_amdgcn_global_load_lds(
        (const __attribute__((address_space(1))) unsigned int*)g,
        (__attribute__((address_space(3))) unsigned int*)l, 16, 0, 0);
}

// ---------------------------------------------------------------------------
// LN normalize one row -> bf16 (wave per row).
// ---------------------------------------------------------------------------
template<int K>
static __device__ __forceinline__ void ln_norm_row(
    const float* __restrict__ x, const float* __restrict__ g,
    const float* __restrict__ bta, ushort* __restrict__ y, int row, int lane)
{
    const float* xp = x + (size_t)row * K;
    constexpr int NV = K / 256;
    float4 v[NV];
    float s = 0.f;
#pragma unroll
    for (int i = 0; i < NV; ++i) {
        v[i] = *(const float4*)(xp + lane * 4 + i * 256);
        s += v[i].x + v[i].y + v[i].z + v[i].w;
    }
#pragma unroll
    for (int o = 1; o < 64; o <<= 1) s += __shfl_xor(s, o, 64);
    const float mu = s * (1.0f / K);
    float vs = 0.f;
#pragma unroll
    for (int i = 0; i < NV; ++i) {
        float dx = v[i].x - mu, dy = v[i].y - mu, dz = v[i].z - mu, dw = v[i].w - mu;
        vs += dx * dx + dy * dy + dz * dz + dw * dw;
    }
#pragma unroll
    for (int o = 1; o < 64; o <<= 1) vs += __shfl_xor(vs, o, 64);
    const float rs = rsqrtf(vs * (1.0f / K) + EPS_LN);
#pragma unroll
    for (int i = 0; i < NV; ++i) {
        const float4 gv = *(const float4*)(g   + lane * 4 + i * 256);
        const float4 bv = *(const float4*)(bta + lane * 4 + i * 256);
        uint2 o;
        o.x = pk_bf16((v[i].x - mu) * rs * gv.x + bv.x, (v[i].y - mu) * rs * gv.y + bv.y);
        o.y = pk_bf16((v[i].z - mu) * rs * gv.z + bv.z, (v[i].w - mu) * rs * gv.w + bv.w);
        *(uint2*)(y + (size_t)row * K + lane * 4 + i * 256) = o;
    }
}

// LN stats only (K=1024), wave per row.
static __device__ __forceinline__ void ln_stats_row(
    const float* __restrict__ x, float* __restrict__ mean, float* __restrict__ rstd,
    int row, int lane)
{
    const float* xp = x + (size_t)row * QDIM;
    float4 v[4];
    float s = 0.f;
#pragma unroll
    for (int i = 0; i < 4; ++i) {
        v[i] = *(const float4*)(xp + lane * 4 + i * 256);
        s += v[i].x + v[i].y + v[i].z + v[i].w;
    }
#pragma unroll
    for (int o = 1; o < 64; o <<= 1) s += __shfl_xor(s, o, 64);
    const float mu = s * (1.0f / QDIM);
    float vs = 0.f;
#pragma unroll
    for (int i = 0; i < 4; ++i) {
        float dx = v[i].x - mu, dy = v[i].y - mu, dz = v[i].z - mu, dw = v[i].w - mu;
        vs += dx * dx + dy * dy + dz * dz + dw * dw;
    }
#pragma unroll
    for (int o = 1; o < 64; o <<= 1) vs += __shfl_xor(vs, o, 64);
    if (lane == 0) {
        mean[row] = mu;
        rstd[row] = rsqrtf(vs * (1.0f / QDIM) + EPS_LN);
    }
}

// 64x64 transpose tile: dst[n][k] = bf16(src[k][n]), src is [K][256].
static __device__ __forceinline__ void wt_transpose_body(
    const float* __restrict__ src, ushort* __restrict__ dst, int K,
    int kx, int ny, int t, ushort (*Ts)[72])
{
    const int k0 = kx * 64, n0 = ny * 64;
    const int nl = t & 63;
#pragma unroll
    for (int p = 0; p < 16; ++p) {
        const int kl = p * 4 + (t >> 6);
        Ts[nl][kl] = f2bf(src[(size_t)(k0 + kl) * 256 + n0 + nl]);
    }
    __syncthreads();
    const int ck = (t & 7) * 8;
#pragma unroll
    for (int p = 0; p < 2; ++p) {
        const int rn = p * 32 + (t >> 3);
        *(bf16x8*)(dst + (size_t)(n0 + rn) * K + k0 + ck) = *(const bf16x8*)&Ts[rn][ck];
    }
}

// ---------------------------------------------------------------------------
// Phase A (one launch): KV normalize (8192 blk) + Q LN stats (512 blk)
// + Wq/Wk/Wv transposes (64+32+32 blk). 256 threads.
// ---------------------------------------------------------------------------
__global__ __launch_bounds__(256) void phaseA_kernel(
    const float* __restrict__ inputs, const float* __restrict__ ln2g,
    const float* __restrict__ ln2b,   ushort* __restrict__ Abf,
    const float* __restrict__ hidden, float* __restrict__ mean_h, float* __restrict__ rstd_h,
    const float* __restrict__ Wq, const float* __restrict__ Wk, const float* __restrict__ Wv,
    ushort* __restrict__ WtQ, ushort* __restrict__ WtKV)
{
    __shared__ ushort Ts[64][72];
    const int bid = blockIdx.x;
    const int t = threadIdx.x;
    const int lane = t & 63;
    if (bid < 8192) {
        ln_norm_row<KVDIM>(inputs, ln2g, ln2b, Abf, bid * 4 + (t >> 6), lane);
    } else if (bid < 8704) {
        ln_stats_row(hidden, mean_h, rstd_h, (bid - 8192) * 4 + (t >> 6), lane);
    } else if (bid < 8768) {
        const int p = bid - 8704;
        wt_transpose_body(Wq, WtQ, QDIM, p & 15, p >> 4, t, Ts);
    } else if (bid < 8800) {
        const int p = bid - 8768;
        wt_transpose_body(Wk, WtKV, KVDIM, p & 7, p >> 3, t, Ts);
    } else {
        const int p = bid - 8800;
        wt_transpose_body(Wv, WtKV + (size_t)256 * KVDIM, KVDIM, p & 7, p >> 3, t, Ts);
    }
}

// ---------------------------------------------------------------------------
// Phase B (one launch, 256 thr): blocks [0,2048) = KV GEMM (64x128, BK=64),
// blocks [2048,2176) = Q GEMM (64x64, BK=64, LN fused into A staging).
// ---------------------------------------------------------------------------
__global__ __launch_bounds__(256, 3) void phaseB_kernel(
    const ushort* __restrict__ Abf, const ushort* __restrict__ WtKV,
    const float* __restrict__ bk, const float* __restrict__ bv,
    ushort* __restrict__ kb, ushort* __restrict__ vt,
    const float* __restrict__ hidden, const float* __restrict__ mean_h,
    const float* __restrict__ rstd_h,
    const float* __restrict__ ln1g, const float* __restrict__ ln1b,
    const ushort* __restrict__ WtQ, const float* __restrict__ bq,
    ushort* __restrict__ qb, float oscale)
{
    __shared__ __align__(16) ushort SMEM[4 * 64 * 72];   // 36864 B
    const int bid  = blockIdx.x;
    const int t    = threadIdx.x;
    const int lane = t & 63;
    const int w    = t >> 6;
    const int lq   = lane & 15;
    const int lg   = lane >> 4;
    const int wm   = w >> 1;
    const int wn   = w & 1;

    if (bid < 2048) {
        // ================= KV GEMM (64x128 tile, BK=64) =================
        const int work = ((bid & 7) << 8) | (bid >> 3);   // XCD-chunked swizzle
        const int bm = (work >> 2) * 64;
        const int bn = (work & 3) * 128;
        ushort* As = SMEM;            // [64][64] swizzled, 4096 ushorts
        ushort* Bs = SMEM + 4096;     // [128][64] swizzled, 8192 ushorts

        const int srow = t >> 3;                              // 0..31
        const int scol = ((t & 7) ^ (srow & 7)) * 8;          // xor-swizzled col
        const ushort* gA = Abf  + (size_t)(bm + srow) * KVDIM + scol;
        const ushort* gB = WtKV + (size_t)(bn + srow) * KVDIM + scol;

        f32x4 acc[4][2] = {};        // wave: rows [0,64) x cols [w*32, +32)
        for (int k0 = 0; k0 < KVDIM; k0 += 64) {
            gld_lds16(gA + k0,                      As + t * 8);
            gld_lds16(gA + (size_t)32 * KVDIM + k0, As + 2048 + t * 8);
#pragma unroll
            for (int p = 0; p < 4; ++p)
                gld_lds16(gB + (size_t)(p * 32) * KVDIM + k0, Bs + p * 2048 + t * 8);
            __syncthreads();
#pragma unroll
            for (int kh = 0; kh < 2; ++kh) {
                bf16x8 af[4], bf[2];
#pragma unroll
                for (int mt = 0; mt < 4; ++mt) {
                    const int m = mt * 16 + lq;
                    af[mt] = *(const bf16x8*)(As + m * 64 + (((lg + 4 * kh) ^ (m & 7)) << 3));
                }
#pragma unroll
                for (int nt = 0; nt < 2; ++nt) {
                    const int n = w * 32 + nt * 16 + lq;
                    bf[nt] = *(const bf16x8*)(Bs + n * 64 + (((lg + 4 * kh) ^ (n & 7)) << 3));
                }
#pragma unroll
                for (int mt = 0; mt < 4; ++mt)
#pragma unroll
                    for (int nt = 0; nt < 2; ++nt)
                        acc[mt][nt] = __builtin_amdgcn_mfma_f32_16x16x32_bf16(af[mt], bf[nt], acc[mt][nt], 0, 0, 0);
            }
            __syncthreads();
        }
        // Post-loop: per-wave epilogue scratch (SMEM + w*2560), no cross-wave use.
        const int bidx = bm >> 13;
        const int tokb = bm & 8191;
        const int nc0  = bn + w * 32;          // wave's output-col base (mult of 32)

        if (bn < 256) {
            // ---- K path: Cs[tok 64][col 32] (stride 40) -> 16B row stores ----
            ushort* Cs = SMEM + w * 2560;
#pragma unroll
            for (int nt = 0; nt < 2; ++nt) {
                const int n_l = nt * 16 + lq;
                const float bias = bk[nc0 + n_l];
#pragma unroll
                for (int mt = 0; mt < 4; ++mt)
#pragma unroll
                    for (int r = 0; r < 4; ++r)
                        Cs[(mt * 16 + lg * 4 + r) * 40 + n_l] = f2bf(acc[mt][nt][r] + bias);
            }
            const int r0 = lane >> 2;          // 0..15
            const int ck = (lane & 3) * 8;     // 0..24
            const int h  = nc0 >> 5;           // one head per wave
            const size_t obase = (((size_t)(bidx * NH + h) << 13) + tokb) * 32 + ck;
#pragma unroll
            for (int p = 0; p < 4; ++p) {
                const int row = p * 16 + r0;
                *(bf16x8*)(kb + obase + (size_t)row * 32) = *(const bf16x8*)&Cs[row * 40 + ck];
            }
        } else {
            // ---- V path: Cs[col 32][tok 64] (stride 72) -> vT 16B stores ----
            ushort* Cs = SMEM + w * 2560;
#pragma unroll
            for (int nt = 0; nt < 2; ++nt) {
                const int n_l = nt * 16 + lq;
                const float bias = bv[(nc0 - 256) + n_l];
#pragma unroll
                for (int mt = 0; mt < 4; ++mt) {
                    uint2 o;
                    o.x = pk_bf16(acc[mt][nt][0] + bias, acc[mt][nt][1] + bias);
                    o.y = pk_bf16(acc[mt][nt][2] + bias, acc[mt][nt][3] + bias);
                    *(uint2*)&Cs[n_l * 72 + mt * 16 + lg * 4] = o;
                }
            }
            const int r0 = lane >> 3;          // 0..7
            const int cm = (lane & 7) * 8;     // 0..56
            const int nv0 = nc0 - 256;
            const int h  = nv0 >> 5;           // one head per wave
            const int tokc = tokb + cm;
#pragma unroll
            for (int p = 0; p < 4; ++p) {
                const int row = p * 8 + r0;    // 0..31 = d within head
                *(bf16x8*)(vt + ((size_t)(bidx * NH + h) * 32 + row) * LKV + tokc) =
                    *(const bf16x8*)&Cs[row * 72 + cm];
            }
        }
    } else {
        // ================= Q GEMM (LN fused) =================
        const int p  = bid - 2048;
        const int bm = (p >> 2) * 64;
        const int bn = (p & 3) * 64;
        ushort* As = SMEM;
        ushort* Bs = SMEM + 4096;

        const int srow = t >> 3;                              // 0..31
        const int scol = ((t & 7) ^ (srow & 7)) * 8;          // xor-swizzled col
        const ushort* gB = WtQ + (size_t)(bn + srow) * QDIM + scol;
        ushort* lB  = Bs + t * 8;
        ushort* lA0 = As + t * 8;
        ushort* lA1 = As + 2048 + t * 8;

        const int r0 = bm + srow;
        const float mu0 = mean_h[r0],      rs0 = rstd_h[r0];
        const float mu1 = mean_h[r0 + 32], rs1 = rstd_h[r0 + 32];
        const float* xA0 = hidden + (size_t)r0 * QDIM + scol;
        const float* xA1 = xA0 + (size_t)32 * QDIM;

        f32x4 acc[2][2] = {};
        for (int k0 = 0; k0 < QDIM; k0 += 64) {
            gld_lds16(gB + k0,                      lB);
            gld_lds16(gB + (size_t)32 * QDIM + k0,  lB + 2048);
            const float4 a0 = *(const float4*)(xA0 + k0);
            const float4 a1 = *(const float4*)(xA0 + k0 + 4);
            const float4 c0 = *(const float4*)(xA1 + k0);
            const float4 c1 = *(const float4*)(xA1 + k0 + 4);
            const float4 g0 = *(const float4*)(ln1g + k0 + scol);
            const float4 g1 = *(const float4*)(ln1g + k0 + scol + 4);
            const float4 d0 = *(const float4*)(ln1b + k0 + scol);
            const float4 d1 = *(const float4*)(ln1b + k0 + scol + 4);
            uint4 w0, w1;
            w0.x = pk_bf16((a0.x - mu0) * rs0 * g0.x + d0.x, (a0.y - mu0) * rs0 * g0.y + d0.y);
            w0.y = pk_bf16((a0.z - mu0) * rs0 * g0.z + d0.z, (a0.w - mu0) * rs0 * g0.w + d0.w);
            w0.z = pk_bf16((a1.x - mu0) * rs0 * g1.x + d1.x, (a1.y - mu0) * rs0 * g1.y + d1.y);
            w0.w = pk_bf16((a1.z - mu0) * rs0 * g1.z + d1.z, (a1.w - mu0) * rs0 * g1.w + d1.w);
            w1.x = pk_bf16((c0.x - mu1) * rs1 * g0.x + d0.x, (c0.y - mu1) * rs1 * g0.y + d0.y);
            w1.y = pk_bf16((c0.z - mu1) * rs1 * g0.z + d0.z, (c0.w - mu1) * rs1 * g0.w + d0.w);
            w1.z = pk_bf16((c1.x - mu1) * rs1 * g1.x + d1.x, (c1.y - mu1) * rs1 * g1.y + d1.y);
            w1.w = pk_bf16((c1.z - mu1) * rs1 * g1.z + d1.z, (c1.w - mu1) * rs1 * g1.w + d1.w);
            *(uint4*)lA0 = w0;
            *(uint4*)lA1 = w1;
            __syncthreads();
#pragma unroll
            for (int kh = 0; kh < 2; ++kh) {
                bf16x8 af[2], bf[2];
#pragma unroll
                for (int mt = 0; mt < 2; ++mt) {
                    const int m = wm * 32 + mt * 16 + lq;
                    af[mt] = *(const bf16x8*)(As + m * 64 + (((lg + 4 * kh) ^ (m & 7)) << 3));
                }
#pragma unroll
                for (int nt = 0; nt < 2; ++nt) {
                    const int n = wn * 32 + nt * 16 + lq;
                    bf[nt] = *(const bf16x8*)(Bs + n * 64 + (((lg + 4 * kh) ^ (n & 7)) << 3));
                }
#pragma unroll
                for (int mt = 0; mt < 2; ++mt)
#pragma unroll
                    for (int nt = 0; nt < 2; ++nt)
                        acc[mt][nt] = __builtin_amdgcn_mfma_f32_16x16x32_bf16(af[mt], bf[nt], acc[mt][nt], 0, 0, 0);
            }
            __syncthreads();
        }

#pragma unroll
        for (int nt = 0; nt < 2; ++nt) {
            const int n = bn + wn * 32 + nt * 16 + lq;
            const int h = n >> 5, d = n & 31;
            const float bias = bq[n];
#pragma unroll
            for (int mt = 0; mt < 2; ++mt) {
                const int m0   = bm + wm * 32 + mt * 16 + lg * 4;
                const int bidx = m0 >> 9;
                const int tok  = m0 & 511;
                const size_t base = (((size_t)(bidx * NH + h) << 9) + tok) * 32 + d;
#pragma unroll
                for (int r = 0; r < 4; ++r)
                    qb[base + (size_t)r * 32] = f2bf((acc[mt][nt][r] + bias) * oscale);
            }
        }
    }
}

// ---------------------------------------------------------------------------
// MFMA flash attention, fixed-baseline softmax, 64-KV iterations.
// Q-TILE 128 ROWS (NQ=8): K/V traffic halves again, 256MB -> 128MB through
// the L2-miss/L3 path (measured ~5.8 TB/s at q64 => ~22us floor). Softmax+PV
// now per-(z,n): each n-chain is 2 QK MFMA -> 8 exp2 -> pack -> permlane ->
// 2 PV MFMA with ~16 transient regs; 8 independent chains give ILP. Live set
// ~165 regs (qfrag 32 + oacc 64 + kc/vc 32) -> launch_bounds(256,2), cap 256,
// no spill (occupancy proved a non-lever in rounds 2-5; 64 loads/CU in
// flight cover L3 latency). Grid 512 = 32 bh x 4 qt128 x 4 KV-quarters,
// bh-major per XCD. Wave w owns KV [quarter*2048 + w*512, +512) = 8 iters.
// Partials per quarter; attn_combine merges 4.
// ---------------------------------------------------------------------------
#define NQ 8
__global__ __launch_bounds__(256, 2) void attn_mfma_kernel(
    const ushort* __restrict__ Qb,  // [B*H][LQ][32] bf16, pre-scaled by log2e/sqrt(32)
    const ushort* __restrict__ Kb,  // [B*H][LKV][32]
    const ushort* __restrict__ Vt,  // [B*H][32][LKV]
    float* __restrict__ Opart,      // [4][32][4][128q][32d] f32 partials
    float* __restrict__ lpart)      // [4][32][4][128q] f32 partials
{
    const int bid = blockIdx.x;
    const int xcd = bid & 7;
    const int u   = bid >> 3;                // 0..63, sequential within an XCD
    const int bhw = u >> 4;                  // 0..3  bh-within-XCD (MAJOR)
    const int r2  = u & 15;
    const int qt  = r2 >> 2;                 // 0..3 (q-tile of 128)
    const int quarter = r2 & 3;              // 0..3: KV quarter [q*2048, +2048)
    const int bh  = (bhw << 3) | xcd;        // bh pinned to one XCD
    const int t = threadIdx.x, w = t >> 6, lane = t & 63;
    const int lq = lane & 15, lg = lane >> 4;

    __shared__ __align__(16) float Ob[2 * 128 * 36];   // 36864 B combine scratch
    __shared__ float lbuf[4][128];

    // Q frags (B operand of QK): lane holds Q[q=n*16+lq][k=lg*8+j]
    bf16x8 qfrag[NQ];
    const size_t qbase = ((size_t)bh * LQ + qt * 128) * 32;
#pragma unroll
    for (int n = 0; n < NQ; ++n)
        qfrag[n] = *(const bf16x8*)(Qb + qbase + (size_t)(n * 16 + lq) * 32 + lg * 8);

    const int kv0 = quarter * 2048 + w * 512;
    const ushort* KpA = Kb + ((size_t)bh * LKV + kv0 + lq) * 32 + lg * 8;
    const ushort* VpA = Vt + ((size_t)bh * 32 + lq) * LKV + kv0 + lg * 8;

    f32x4 oacc[2][NQ] = {};        // [d-tile][q-tile]
    float l_part[NQ] = {};
    const f32x4 cM = {-SMAX, -SMAX, -SMAX, -SMAX};

    for (int kt = 0; kt < 512; kt += 64) {
        // K frags (A operand of QK: lane = K[kv=m*16+lq][k=lg*8+j])
        bf16x8 kc[4];
#pragma unroll
        for (int m = 0; m < 4; ++m)
            kc[m] = *(const bf16x8*)(KpA + (size_t)(kt + m * 16) * 32);
        // V frags (A operand of PV): V^T[d=dt*16+lq][kv=kt+z*32+lg*8+j]
        bf16x8 vc[2][2];
#pragma unroll
        for (int dt = 0; dt < 2; ++dt)
#pragma unroll
            for (int z = 0; z < 2; ++z)
                vc[dt][z] = *(const bf16x8*)(VpA + (size_t)(dt * 16) * LKV + kt + z * 32);

        // per (z, n): QK -> exp2 -> permlane interleave -> PV, minimal
        // transient registers, 8 independent n-chains for ILP.
#pragma unroll
        for (int z = 0; z < 2; ++z) {
#pragma unroll
            for (int n = 0; n < NQ; ++n) {
                f32x4 s0 = __builtin_amdgcn_mfma_f32_16x16x32_bf16(kc[2 * z],     qfrag[n], cM, 0, 0, 0);
                f32x4 s1 = __builtin_amdgcn_mfma_f32_16x16x32_bf16(kc[2 * z + 1], qfrag[n], cM, 0, 0, 0);
                const float e0 = EXP2F(s0[0]);
                const float e1 = EXP2F(s0[1]);
                const float e2 = EXP2F(s0[2]);
                const float e3 = EXP2F(s0[3]);
                const float f0 = EXP2F(s1[0]);
                const float f1 = EXP2F(s1[1]);
                const float f2 = EXP2F(s1[2]);
                const float f3 = EXP2F(s1[3]);
                l_part[n] += ((e0 + e1) + (e2 + e3)) + ((f0 + f1) + (f2 + f3));
                unsigned int wa = pk_bf16(e0, e1);
                unsigned int wb = pk_bf16(e2, e3);
                unsigned int wc = pk_bf16(f0, f1);
                unsigned int wd = pk_bf16(f2, f3);
                interleave_swap(wa, wc, lane);   // wa=W0, wc=W2
                interleave_swap(wb, wd, lane);   // wb=W1, wd=W3
                uint4 wv;
                wv.x = wa; wv.y = wb; wv.z = wc; wv.w = wd;
                const bf16x8 pfz = __builtin_bit_cast(bf16x8, wv);
                oacc[0][n] = __builtin_amdgcn_mfma_f32_16x16x32_bf16(vc[0][z], pfz, oacc[0][n], 0, 0, 0);
                oacc[1][n] = __builtin_amdgcn_mfma_f32_16x16x32_bf16(vc[1][z], pfz, oacc[1][n], 0, 0, 0);
            }
        }
    }

    // ---- l reduce + 4-wave combine -> partial write ----
#pragma unroll
    for (int n = 0; n < NQ; ++n) {
        l_part[n] += __shfl_xor(l_part[n], 16);
        l_part[n] += __shfl_xor(l_part[n], 32);
    }
    if (lg == 0) {
#pragma unroll
        for (int n = 0; n < NQ; ++n)
            lbuf[w][n * 16 + lq] = l_part[n];
    }
    if (w >= 2) {
#pragma unroll
        for (int n = 0; n < NQ; ++n)
#pragma unroll
            for (int dt = 0; dt < 2; ++dt)
                *(f32x4*)&Ob[((size_t)(w - 2) * 128 + n * 16 + lq) * 36 + dt * 16 + lg * 4] = oacc[dt][n];
    }
    __syncthreads();
    if (w < 2) {
#pragma unroll
        for (int n = 0; n < NQ; ++n)
#pragma unroll
            for (int dt = 0; dt < 2; ++dt) {
                float* p = &Ob[((size_t)w * 128 + n * 16 + lq) * 36 + dt * 16 + lg * 4];
                f32x4 v = *(f32x4*)p;
                v += oacc[dt][n];
                *(f32x4*)p = v;
            }
    }
    __syncthreads();
    {
        const int pidx = (quarter * 32 + bh) * 4 + qt;
        const int q  = t >> 3;           // 0..31
        const int d0 = (t & 7) * 4;      // 0..28
#pragma unroll
        for (int rh = 0; rh < 4; ++rh) {
            const int row = q + rh * 32;
            f32x4 s0 = *(const f32x4*)&Ob[((size_t)row) * 36 + d0];
            f32x4 s1 = *(const f32x4*)&Ob[((size_t)(128 + row)) * 36 + d0];
            s0 += s1;
            *(f32x4*)(Opart + (size_t)pidx * 4096 + row * 32 + d0) = s0;
            if ((t & 7) == 0) {
                float gl = lbuf[0][row] + lbuf[1][row] + lbuf[2][row] + lbuf[3][row];
                lpart[(size_t)pidx * 128 + row] = gl;
            }
        }
    }
}

// ---------------------------------------------------------------------------
// Combine the 4 KV-quarter partials: Out = sum(Oq)/sum(lq). Grid 128 =
// bh*4+qt, 256 thr, 4 x float4 per thread.
// ---------------------------------------------------------------------------
__global__ __launch_bounds__(256) void attn_combine_kernel(
    const float* __restrict__ Opart, const float* __restrict__ lpart,
    float* __restrict__ Out)
{
    const int cb = blockIdx.x;               // 0..127
    const int bh = cb >> 2, qt = cb & 3;
    const int b = bh >> 3, h = bh & 7;
    const int t = threadIdx.x;
    const int q = t >> 3;                    // 0..31
    const int dq = (t & 7) * 4;              // 0..28
#pragma unroll
    for (int rh = 0; rh < 4; ++rh) {
        const int row = q + rh * 32;
        float4 o = {0.f, 0.f, 0.f, 0.f};
        float l = 0.f;
#pragma unroll
        for (int j = 0; j < 4; ++j) {
            const size_t pidx = (size_t)((j * 32 + bh) * 4 + qt);
            const float4 a = *(const float4*)(Opart + pidx * 4096 + row * 32 + dq);
            o.x += a.x; o.y += a.y; o.z += a.z; o.w += a.w;
            l += lpart[pidx * 128 + row];
        }
        const float inv = 1.0f / l;
        o.x *= inv; o.y *= inv; o.z *= inv; o.w *= inv;
        *(float4*)(Out + ((size_t)b * LQ + qt * 128 + row) * 256 + h * 32 + dq) = o;
    }
}

// ---------------------------------------------------------------------------
extern "C" void kernel_launch(void* const* d_in, const int* in_sizes, int n_in,
                              void* d_out, int out_size, void* d_ws, size_t ws_size,
                              hipStream_t stream)
{
    const float* hidden = (const float*)d_in[0];
    const float* inputs = (const float*)d_in[1];
    const float* ln1g   = (const float*)d_in[2];
    const float* ln1b   = (const float*)d_in[3];
    const float* ln2g   = (const float*)d_in[4];
    const float* ln2b   = (const float*)d_in[5];
    const float* Wq     = (const float*)d_in[6];
    const float* bq     = (const float*)d_in[7];
    const float* Wk     = (const float*)d_in[8];
    const float* bk     = (const float*)d_in[9];
    const float* Wv     = (const float*)d_in[10];
    const float* bv     = (const float*)d_in[11];
    float* out = (float*)d_out;

    // workspace (bytes), total ~66 MB
    char* wsb = (char*)d_ws;
    ushort* qb     = (ushort*)(wsb);                               // 1 MB   [32][512][32]
    ushort* WtKV   = (ushort*)(wsb + (1u << 20));                  // 0.5 MB [512][512]
    ushort* WtQ    = (ushort*)(wsb + (1u << 20) + (512u << 10));   // 0.5 MB [256][1024]
    float*  mean_h = (float*)(wsb + (2u << 20));                   // 8 KB
    float*  rstd_h = (float*)(wsb + (2u << 20) + 8192);            // 8 KB
    ushort* kb     = (ushort*)(wsb + (2u << 20) + 16384);          // 16 MB  [32][8192][32]
    ushort* vt     = (ushort*)(wsb + (18u << 20) + 16384);         // 16 MB  [32][32][8192]
    ushort* Abf    = (ushort*)(wsb + (34u << 20) + 16384);         // 32 MB  [32768][512]

    // Attention partials alias Abf (dead after phaseB): 8 MB + 256 KB << 32 MB
    float* Opart = (float*)Abf;                        // [4][32][4][128][32] f32
    float* lpart = Opart + (size_t)4 * 32 * 4 * 4096;  // [4][32][4][128] f32

    const float oscale = 0.2550540226496112f;   // log2(e)/sqrt(32): log2-domain softmax

    phaseA_kernel<<<8832, 256, 0, stream>>>(inputs, ln2g, ln2b, Abf,
                                            hidden, mean_h, rstd_h,
                                            Wq, Wk, Wv, WtQ, WtKV);
    phaseB_kernel<<<2176, 256, 0, stream>>>(Abf, WtKV, bk, bv, kb, vt,
                                            hidden, mean_h, rstd_h, ln1g, ln1b,
                                            WtQ, bq, qb, oscale);
    attn_mfma_kernel<<<512, 256, 0, stream>>>(qb, kb, vt, Opart, lpart);
    attn_combine_kernel<<<128, 256, 0, stream>>>(Opart, lpart, out);
}

// Round 10
// 199.199 us; speedup vs baseline: 1.0993x; 1.0140x over previous
//
#include <hip/hip_runtime.h>
#include <hip/hip_bf16.h>
#include <math.h>

// Problem constants
#define NB    4
#define LQ    512
#define LKV   8192
#define QDIM  1024
#define KVDIM 512
#define NH    8
#define EPS_LN 1e-5f
#define SMAX  12.0f     // fixed softmax baseline (log2 domain); scores*log2e max ~9

typedef __attribute__((ext_vector_type(8))) short bf16x8;
typedef __attribute__((ext_vector_type(4))) float f32x4;

static __device__ __forceinline__ ushort f2bf(float x) {
    unsigned int u = __builtin_bit_cast(unsigned int, x);
    u += 0x7FFFu + ((u >> 16) & 1u);          // round-to-nearest-even
    return (ushort)(u >> 16);
}

#if __has_builtin(__builtin_amdgcn_cvt_pk_bf16_f32)
static __device__ __forceinline__ unsigned int pk_bf16(float a, float b) {
    auto r = __builtin_amdgcn_cvt_pk_bf16_f32(a, b);
    return __builtin_bit_cast(unsigned int, r);
}
#else
static __device__ __forceinline__ unsigned int pk_bf16(float a, float b) {
    return (unsigned int)f2bf(a) | ((unsigned int)f2bf(b) << 16);
}
#endif

#if __has_builtin(__builtin_amdgcn_exp2f)
#define EXP2F(x) __builtin_amdgcn_exp2f(x)
#else
#define EXP2F(x) exp2f(x)
#endif

// In-register 4-row interleave across 16-lane groups:
//   x in rows [a0,a1,a2,a3], y in rows [b0,b1,b2,b3]  (rows = 16-lane groups)
//   -> x = [a0,a2,b0,b2], y = [a1,a3,b1,b3]
// Used to convert the MFMA C/D row grouping (lg*4+r) into the K=32 B-operand
// grouping (lg*8+j) without touching LDS. permlane*_swap are full-rate VALU.
static __device__ __forceinline__ void interleave_swap(unsigned int &x, unsigned int &y, int lane) {
#if __has_builtin(__builtin_amdgcn_permlane32_swap) && __has_builtin(__builtin_amdgcn_permlane16_swap)
    {
        auto r1 = __builtin_amdgcn_permlane32_swap(x, y, false, false);
        auto r2 = __builtin_amdgcn_permlane16_swap(r1[0], r1[1], false, false);
        x = (unsigned int)r2[0];
        y = (unsigned int)r2[1];
    }
#else
    {
        // pl32swap: A2={x.r0,x.r1,y.r0,y.r1}, C2={x.r2,x.r3,y.r2,y.r3}
        unsigned int xs = (unsigned int)__shfl_xor((int)x, 32, 64);
        unsigned int ys = (unsigned int)__shfl_xor((int)y, 32, 64);
        unsigned int A2 = (lane & 32) ? ys : x;
        unsigned int C2 = (lane & 32) ? y  : xs;
        // pl16swap: x'={A2.r0,C2.r0,A2.r2,C2.r2}, y'={A2.r1,C2.r1,A2.r3,C2.r3}
        unsigned int A2x = (unsigned int)__shfl_xor((int)A2, 16, 64);
        unsigned int C2x = (unsigned int)__shfl_xor((int)C2, 16, 64);
        x = (lane & 16) ? C2x : A2;
        y = (lane & 16) ? C2  : A2x;
    }
#endif
}

// async global->LDS, 16B per lane; LDS dest = wave base + lane*16
static __device__ __forceinline__ void gld_lds16(const ushort* g, ushort* l) {
    __builtin_amdgcn_global_load_lds(
        (const __attribute__((address_space(1))) unsigned int*)g,
        (__attribute__((address_space(3))) unsigned int*)l, 16, 0, 0);
}

// ---------------------------------------------------------------------------
// LN normalize one row -> bf16 (wave per row).
// ---------------------------------------------------------------------------
template<int K>
static __device__ __forceinline__ void ln_norm_row(
    const float* __restrict__ x, const float* __restrict__ g,
    const float* __restrict__ bta, ushort* __restrict__ y, int row, int lane)
{
    const float* xp = x + (size_t)row * K;
    constexpr int NV = K / 256;
    float4 v[NV];
    float s = 0.f;
#pragma unroll
    for (int i = 0; i < NV; ++i) {
        v[i] = *(const float4*)(xp + lane * 4 + i * 256);
        s += v[i].x + v[i].y + v[i].z + v[i].w;
    }
#pragma unroll
    for (int o = 1; o < 64; o <<= 1) s += __shfl_xor(s, o, 64);
    const float mu = s * (1.0f / K);
    float vs = 0.f;
#pragma unroll
    for (int i = 0; i < NV; ++i) {
        float dx = v[i].x - mu, dy = v[i].y - mu, dz = v[i].z - mu, dw = v[i].w - mu;
        vs += dx * dx + dy * dy + dz * dz + dw * dw;
    }
#pragma unroll
    for (int o = 1; o < 64; o <<= 1) vs += __shfl_xor(vs, o, 64);
    const float rs = rsqrtf(vs * (1.0f / K) + EPS_LN);
#pragma unroll
    for (int i = 0; i < NV; ++i) {
        const float4 gv = *(const float4*)(g   + lane * 4 + i * 256);
        const float4 bv = *(const float4*)(bta + lane * 4 + i * 256);
        uint2 o;
        o.x = pk_bf16((v[i].x - mu) * rs * gv.x + bv.x, (v[i].y - mu) * rs * gv.y + bv.y);
        o.y = pk_bf16((v[i].z - mu) * rs * gv.z + bv.z, (v[i].w - mu) * rs * gv.w + bv.w);
        *(uint2*)(y + (size_t)row * K + lane * 4 + i * 256) = o;
    }
}

// LN stats only (K=1024), wave per row.
static __device__ __forceinline__ void ln_stats_row(
    const float* __restrict__ x, float* __restrict__ mean, float* __restrict__ rstd,
    int row, int lane)
{
    const float* xp = x + (size_t)row * QDIM;
    float4 v[4];
    float s = 0.f;
#pragma unroll
    for (int i = 0; i < 4; ++i) {
        v[i] = *(const float4*)(xp + lane * 4 + i * 256);
        s += v[i].x + v[i].y + v[i].z + v[i].w;
    }
#pragma unroll
    for (int o = 1; o < 64; o <<= 1) s += __shfl_xor(s, o, 64);
    const float mu = s * (1.0f / QDIM);
    float vs = 0.f;
#pragma unroll
    for (int i = 0; i < 4; ++i) {
        float dx = v[i].x - mu, dy = v[i].y - mu, dz = v[i].z - mu, dw = v[i].w - mu;
        vs += dx * dx + dy * dy + dz * dz + dw * dw;
    }
#pragma unroll
    for (int o = 1; o < 64; o <<= 1) vs += __shfl_xor(vs, o, 64);
    if (lane == 0) {
        mean[row] = mu;
        rstd[row] = rsqrtf(vs * (1.0f / QDIM) + EPS_LN);
    }
}

// 64x64 transpose tile: dst[n][k] = bf16(src[k][n]), src is [K][256].
static __device__ __forceinline__ void wt_transpose_body(
    const float* __restrict__ src, ushort* __restrict__ dst, int K,
    int kx, int ny, int t, ushort (*Ts)[72])
{
    const int k0 = kx * 64, n0 = ny * 64;
    const int nl = t & 63;
#pragma unroll
    for (int p = 0; p < 16; ++p) {
        const int kl = p * 4 + (t >> 6);
        Ts[nl][kl] = f2bf(src[(size_t)(k0 + kl) * 256 + n0 + nl]);
    }
    __syncthreads();
    const int ck = (t & 7) * 8;
#pragma unroll
    for (int p = 0; p < 2; ++p) {
        const int rn = p * 32 + (t >> 3);
        *(bf16x8*)(dst + (size_t)(n0 + rn) * K + k0 + ck) = *(const bf16x8*)&Ts[rn][ck];
    }
}

// ---------------------------------------------------------------------------
// Phase A (one launch): KV normalize (8192 blk) + Q LN stats (512 blk)
// + Wq/Wk/Wv transposes (64+32+32 blk). 256 threads.
// ---------------------------------------------------------------------------
__global__ __launch_bounds__(256) void phaseA_kernel(
    const float* __restrict__ inputs, const float* __restrict__ ln2g,
    const float* __restrict__ ln2b,   ushort* __restrict__ Abf,
    const float* __restrict__ hidden, float* __restrict__ mean_h, float* __restrict__ rstd_h,
    const float* __restrict__ Wq, const float* __restrict__ Wk, const float* __restrict__ Wv,
    ushort* __restrict__ WtQ, ushort* __restrict__ WtKV)
{
    __shared__ ushort Ts[64][72];
    const int bid = blockIdx.x;
    const int t = threadIdx.x;
    const int lane = t & 63;
    if (bid < 8192) {
        ln_norm_row<KVDIM>(inputs, ln2g, ln2b, Abf, bid * 4 + (t >> 6), lane);
    } else if (bid < 8704) {
        ln_stats_row(hidden, mean_h, rstd_h, (bid - 8192) * 4 + (t >> 6), lane);
    } else if (bid < 8768) {
        const int p = bid - 8704;
        wt_transpose_body(Wq, WtQ, QDIM, p & 15, p >> 4, t, Ts);
    } else if (bid < 8800) {
        const int p = bid - 8768;
        wt_transpose_body(Wk, WtKV, KVDIM, p & 7, p >> 3, t, Ts);
    } else {
        const int p = bid - 8800;
        wt_transpose_body(Wv, WtKV + (size_t)256 * KVDIM, KVDIM, p & 7, p >> 3, t, Ts);
    }
}

// ---------------------------------------------------------------------------
// Phase B (one launch, 256 thr): blocks [0,2048) = KV GEMM (64x128, BK=64,
// DOUBLE-BUFFERED single-barrier pipeline), blocks [2048,2176) = Q GEMM.
// KV k-step was {stage -> drain vmcnt(0) -> barrier -> compute -> barrier}:
// every step paid full staging latency serially (MfmaUtil 15%, all pipes
// <25% busy). Now {issue STAGE(i+1) -> compute(i) -> __syncthreads()}: the
// prefetch's ~300-900cyc latency hides under the ds_read+MFMA section, and
// one barrier/step (emits vmcnt(0)+barrier) both drains the prefetch and
// fences the buffer swap. LDS 48KB (2x A-buf + 2x B-buf) -> 3 blocks/CU.
// ---------------------------------------------------------------------------
__global__ __launch_bounds__(256, 3) void phaseB_kernel(
    const ushort* __restrict__ Abf, const ushort* __restrict__ WtKV,
    const float* __restrict__ bk, const float* __restrict__ bv,
    ushort* __restrict__ kb, ushort* __restrict__ vt,
    const float* __restrict__ hidden, const float* __restrict__ mean_h,
    const float* __restrict__ rstd_h,
    const float* __restrict__ ln1g, const float* __restrict__ ln1b,
    const ushort* __restrict__ WtQ, const float* __restrict__ bq,
    ushort* __restrict__ qb, float oscale)
{
    __shared__ __align__(16) ushort SMEM[24576];   // 49152 B
    const int bid  = blockIdx.x;
    const int t    = threadIdx.x;
    const int lane = t & 63;
    const int w    = t >> 6;
    const int lq   = lane & 15;
    const int lg   = lane >> 4;
    const int wm   = w >> 1;
    const int wn   = w & 1;

    if (bid < 2048) {
        // ================= KV GEMM (64x128 tile, BK=64, dbuf) =================
        const int work = ((bid & 7) << 8) | (bid >> 3);   // XCD-chunked swizzle
        const int bm = (work >> 2) * 64;
        const int bn = (work & 3) * 128;
        // buffers: As buf b at SMEM + b*4096 (64x64), Bs buf b at SMEM+8192 + b*8192 (128x64)

        const int srow = t >> 3;                              // 0..31
        const int scol = ((t & 7) ^ (srow & 7)) * 8;          // xor-swizzled col
        const ushort* gA = Abf  + (size_t)(bm + srow) * KVDIM + scol;
        const ushort* gB = WtKV + (size_t)(bn + srow) * KVDIM + scol;

#define STAGE_KV(buf, k0) do {                                              \
        ushort* a_ = SMEM + (buf) * 4096;                                   \
        ushort* b_ = SMEM + 8192 + (buf) * 8192;                            \
        gld_lds16(gA + (k0),                          a_ + t * 8);          \
        gld_lds16(gA + (size_t)32 * KVDIM + (k0),     a_ + 2048 + t * 8);   \
        gld_lds16(gB + (k0),                          b_ + t * 8);          \
        gld_lds16(gB + (size_t)32 * KVDIM + (k0),     b_ + 2048 + t * 8);   \
        gld_lds16(gB + (size_t)64 * KVDIM + (k0),     b_ + 4096 + t * 8);   \
        gld_lds16(gB + (size_t)96 * KVDIM + (k0),     b_ + 6144 + t * 8);   \
    } while (0)

        f32x4 acc[4][2] = {};        // wave: rows [0,64) x cols [w*32, +32)
        STAGE_KV(0, 0);
        __syncthreads();
        for (int i = 0; i < 8; ++i) {
            const int cur = i & 1;
            if (i < 7) STAGE_KV(cur ^ 1, (i + 1) * 64);   // prefetch overlaps compute
            const ushort* a_ = SMEM + cur * 4096;
            const ushort* b_ = SMEM + 8192 + cur * 8192;
#pragma unroll
            for (int kh = 0; kh < 2; ++kh) {
                bf16x8 af[4], bf[2];
#pragma unroll
                for (int mt = 0; mt < 4; ++mt) {
                    const int m = mt * 16 + lq;
                    af[mt] = *(const bf16x8*)(a_ + m * 64 + (((lg + 4 * kh) ^ (m & 7)) << 3));
                }
#pragma unroll
                for (int nt = 0; nt < 2; ++nt) {
                    const int n = w * 32 + nt * 16 + lq;
                    bf[nt] = *(const bf16x8*)(b_ + n * 64 + (((lg + 4 * kh) ^ (n & 7)) << 3));
                }
#pragma unroll
                for (int mt = 0; mt < 4; ++mt)
#pragma unroll
                    for (int nt = 0; nt < 2; ++nt)
                        acc[mt][nt] = __builtin_amdgcn_mfma_f32_16x16x32_bf16(af[mt], bf[nt], acc[mt][nt], 0, 0, 0);
            }
            __syncthreads();   // drains prefetch (vmcnt 0) + fences buffer swap
        }
#undef STAGE_KV
        // Post-loop: per-wave epilogue scratch (SMEM + w*2560), no cross-wave use.
        const int bidx = bm >> 13;
        const int tokb = bm & 8191;
        const int nc0  = bn + w * 32;          // wave's output-col base (mult of 32)

        if (bn < 256) {
            // ---- K path: Cs[tok 64][col 32] (stride 40) -> 16B row stores ----
            ushort* Cs = SMEM + w * 2560;
#pragma unroll
            for (int nt = 0; nt < 2; ++nt) {
                const int n_l = nt * 16 + lq;
                const float bias = bk[nc0 + n_l];
#pragma unroll
                for (int mt = 0; mt < 4; ++mt)
#pragma unroll
                    for (int r = 0; r < 4; ++r)
                        Cs[(mt * 16 + lg * 4 + r) * 40 + n_l] = f2bf(acc[mt][nt][r] + bias);
            }
            const int r0 = lane >> 2;          // 0..15
            const int ck = (lane & 3) * 8;     // 0..24
            const int h  = nc0 >> 5;           // one head per wave
            const size_t obase = (((size_t)(bidx * NH + h) << 13) + tokb) * 32 + ck;
#pragma unroll
            for (int p = 0; p < 4; ++p) {
                const int row = p * 16 + r0;
                *(bf16x8*)(kb + obase + (size_t)row * 32) = *(const bf16x8*)&Cs[row * 40 + ck];
            }
        } else {
            // ---- V path: Cs[col 32][tok 64] (stride 72) -> vT 16B stores ----
            ushort* Cs = SMEM + w * 2560;
#pragma unroll
            for (int nt = 0; nt < 2; ++nt) {
                const int n_l = nt * 16 + lq;
                const float bias = bv[(nc0 - 256) + n_l];
#pragma unroll
                for (int mt = 0; mt < 4; ++mt) {
                    uint2 o;
                    o.x = pk_bf16(acc[mt][nt][0] + bias, acc[mt][nt][1] + bias);
                    o.y = pk_bf16(acc[mt][nt][2] + bias, acc[mt][nt][3] + bias);
                    *(uint2*)&Cs[n_l * 72 + mt * 16 + lg * 4] = o;
                }
            }
            const int r0 = lane >> 3;          // 0..7
            const int cm = (lane & 7) * 8;     // 0..56
            const int nv0 = nc0 - 256;
            const int h  = nv0 >> 5;           // one head per wave
            const int tokc = tokb + cm;
#pragma unroll
            for (int p = 0; p < 4; ++p) {
                const int row = p * 8 + r0;    // 0..31 = d within head
                *(bf16x8*)(vt + ((size_t)(bidx * NH + h) * 32 + row) * LKV + tokc) =
                    *(const bf16x8*)&Cs[row * 72 + cm];
            }
        }
    } else {
        // ================= Q GEMM (LN fused) =================
        const int p  = bid - 2048;
        const int bm = (p >> 2) * 64;
        const int bn = (p & 3) * 64;
        ushort* As = SMEM;
        ushort* Bs = SMEM + 4096;

        const int srow = t >> 3;                              // 0..31
        const int scol = ((t & 7) ^ (srow & 7)) * 8;          // xor-swizzled col
        const ushort* gB = WtQ + (size_t)(bn + srow) * QDIM + scol;
        ushort* lB  = Bs + t * 8;
        ushort* lA0 = As + t * 8;
        ushort* lA1 = As + 2048 + t * 8;

        const int r0 = bm + srow;
        const float mu0 = mean_h[r0],      rs0 = rstd_h[r0];
        const float mu1 = mean_h[r0 + 32], rs1 = rstd_h[r0 + 32];
        const float* xA0 = hidden + (size_t)r0 * QDIM + scol;
        const float* xA1 = xA0 + (size_t)32 * QDIM;

        f32x4 acc[2][2] = {};
        for (int k0 = 0; k0 < QDIM; k0 += 64) {
            gld_lds16(gB + k0,                      lB);
            gld_lds16(gB + (size_t)32 * QDIM + k0,  lB + 2048);
            const float4 a0 = *(const float4*)(xA0 + k0);
            const float4 a1 = *(const float4*)(xA0 + k0 + 4);
            const float4 c0 = *(const float4*)(xA1 + k0);
            const float4 c1 = *(const float4*)(xA1 + k0 + 4);
            const float4 g0 = *(const float4*)(ln1g + k0 + scol);
            const float4 g1 = *(const float4*)(ln1g + k0 + scol + 4);
            const float4 d0 = *(const float4*)(ln1b + k0 + scol);
            const float4 d1 = *(const float4*)(ln1b + k0 + scol + 4);
            uint4 w0, w1;
            w0.x = pk_bf16((a0.x - mu0) * rs0 * g0.x + d0.x, (a0.y - mu0) * rs0 * g0.y + d0.y);
            w0.y = pk_bf16((a0.z - mu0) * rs0 * g0.z + d0.z, (a0.w - mu0) * rs0 * g0.w + d0.w);
            w0.z = pk_bf16((a1.x - mu0) * rs0 * g1.x + d1.x, (a1.y - mu0) * rs0 * g1.y + d1.y);
            w0.w = pk_bf16((a1.z - mu0) * rs0 * g1.z + d1.z, (a1.w - mu0) * rs0 * g1.w + d1.w);
            w1.x = pk_bf16((c0.x - mu1) * rs1 * g0.x + d0.x, (c0.y - mu1) * rs1 * g0.y + d0.y);
            w1.y = pk_bf16((c0.z - mu1) * rs1 * g0.z + d0.z, (c0.w - mu1) * rs1 * g0.w + d0.w);
            w1.z = pk_bf16((c1.x - mu1) * rs1 * g1.x + d1.x, (c1.y - mu1) * rs1 * g1.y + d1.y);
            w1.w = pk_bf16((c1.z - mu1) * rs1 * g1.z + d1.z, (c1.w - mu1) * rs1 * g1.w + d1.w);
            *(uint4*)lA0 = w0;
            *(uint4*)lA1 = w1;
            __syncthreads();
#pragma unroll
            for (int kh = 0; kh < 2; ++kh) {
                bf16x8 af[2], bf[2];
#pragma unroll
                for (int mt = 0; mt < 2; ++mt) {
                    const int m = wm * 32 + mt * 16 + lq;
                    af[mt] = *(const bf16x8*)(As + m * 64 + (((lg + 4 * kh) ^ (m & 7)) << 3));
                }
#pragma unroll
                for (int nt = 0; nt < 2; ++nt) {
                    const int n = wn * 32 + nt * 16 + lq;
                    bf[nt] = *(const bf16x8*)(Bs + n * 64 + (((lg + 4 * kh) ^ (n & 7)) << 3));
                }
#pragma unroll
                for (int mt = 0; mt < 2; ++mt)
#pragma unroll
                    for (int nt = 0; nt < 2; ++nt)
                        acc[mt][nt] = __builtin_amdgcn_mfma_f32_16x16x32_bf16(af[mt], bf[nt], acc[mt][nt], 0, 0, 0);
            }
            __syncthreads();
        }

#pragma unroll
        for (int nt = 0; nt < 2; ++nt) {
            const int n = bn + wn * 32 + nt * 16 + lq;
            const int h = n >> 5, d = n & 31;
            const float bias = bq[n];
#pragma unroll
            for (int mt = 0; mt < 2; ++mt) {
                const int m0   = bm + wm * 32 + mt * 16 + lg * 4;
                const int bidx = m0 >> 9;
                const int tok  = m0 & 511;
                const size_t base = (((size_t)(bidx * NH + h) << 9) + tok) * 32 + d;
#pragma unroll
                for (int r = 0; r < 4; ++r)
                    qb[base + (size_t)r * 32] = f2bf((acc[mt][nt][r] + bias) * oscale);
            }
        }
    }
}

// ---------------------------------------------------------------------------
// MFMA flash attention, fixed-baseline softmax, 64-KV iterations.
// Q-tile 128 rows (NQ=8), KV quarters, partials merged by attn_combine.
// (unchanged from round 9)
// ---------------------------------------------------------------------------
#define NQ 8
__global__ __launch_bounds__(256, 2) void attn_mfma_kernel(
    const ushort* __restrict__ Qb,  // [B*H][LQ][32] bf16, pre-scaled by log2e/sqrt(32)
    const ushort* __restrict__ Kb,  // [B*H][LKV][32]
    const ushort* __restrict__ Vt,  // [B*H][32][LKV]
    float* __restrict__ Opart,      // [4][32][4][128q][32d] f32 partials
    float* __restrict__ lpart)      // [4][32][4][128q] f32 partials
{
    const int bid = blockIdx.x;
    const int xcd = bid & 7;
    const int u   = bid >> 3;                // 0..63, sequential within an XCD
    const int bhw = u >> 4;                  // 0..3  bh-within-XCD (MAJOR)
    const int r2  = u & 15;
    const int qt  = r2 >> 2;                 // 0..3 (q-tile of 128)
    const int quarter = r2 & 3;              // 0..3: KV quarter [q*2048, +2048)
    const int bh  = (bhw << 3) | xcd;        // bh pinned to one XCD
    const int t = threadIdx.x, w = t >> 6, lane = t & 63;
    const int lq = lane & 15, lg = lane >> 4;

    __shared__ __align__(16) float Ob[2 * 128 * 36];   // 36864 B combine scratch
    __shared__ float lbuf[4][128];

    // Q frags (B operand of QK): lane holds Q[q=n*16+lq][k=lg*8+j]
    bf16x8 qfrag[NQ];
    const size_t qbase = ((size_t)bh * LQ + qt * 128) * 32;
#pragma unroll
    for (int n = 0; n < NQ; ++n)
        qfrag[n] = *(const bf16x8*)(Qb + qbase + (size_t)(n * 16 + lq) * 32 + lg * 8);

    const int kv0 = quarter * 2048 + w * 512;
    const ushort* KpA = Kb + ((size_t)bh * LKV + kv0 + lq) * 32 + lg * 8;
    const ushort* VpA = Vt + ((size_t)bh * 32 + lq) * LKV + kv0 + lg * 8;

    f32x4 oacc[2][NQ] = {};        // [d-tile][q-tile]
    float l_part[NQ] = {};
    const f32x4 cM = {-SMAX, -SMAX, -SMAX, -SMAX};

    for (int kt = 0; kt < 512; kt += 64) {
        // K frags (A operand of QK: lane = K[kv=m*16+lq][k=lg*8+j])
        bf16x8 kc[4];
#pragma unroll
        for (int m = 0; m < 4; ++m)
            kc[m] = *(const bf16x8*)(KpA + (size_t)(kt + m * 16) * 32);
        // V frags (A operand of PV): V^T[d=dt*16+lq][kv=kt+z*32+lg*8+j]
        bf16x8 vc[2][2];
#pragma unroll
        for (int dt = 0; dt < 2; ++dt)
#pragma unroll
            for (int z = 0; z < 2; ++z)
                vc[dt][z] = *(const bf16x8*)(VpA + (size_t)(dt * 16) * LKV + kt + z * 32);

        // per (z, n): QK -> exp2 -> permlane interleave -> PV, minimal
        // transient registers, 8 independent n-chains for ILP.
#pragma unroll
        for (int z = 0; z < 2; ++z) {
#pragma unroll
            for (int n = 0; n < NQ; ++n) {
                f32x4 s0 = __builtin_amdgcn_mfma_f32_16x16x32_bf16(kc[2 * z],     qfrag[n], cM, 0, 0, 0);
                f32x4 s1 = __builtin_amdgcn_mfma_f32_16x16x32_bf16(kc[2 * z + 1], qfrag[n], cM, 0, 0, 0);
                const float e0 = EXP2F(s0[0]);
                const float e1 = EXP2F(s0[1]);
                const float e2 = EXP2F(s0[2]);
                const float e3 = EXP2F(s0[3]);
                const float f0 = EXP2F(s1[0]);
                const float f1 = EXP2F(s1[1]);
                const float f2 = EXP2F(s1[2]);
                const float f3 = EXP2F(s1[3]);
                l_part[n] += ((e0 + e1) + (e2 + e3)) + ((f0 + f1) + (f2 + f3));
                unsigned int wa = pk_bf16(e0, e1);
                unsigned int wb = pk_bf16(e2, e3);
                unsigned int wc = pk_bf16(f0, f1);
                unsigned int wd = pk_bf16(f2, f3);
                interleave_swap(wa, wc, lane);   // wa=W0, wc=W2
                interleave_swap(wb, wd, lane);   // wb=W1, wd=W3
                uint4 wv;
                wv.x = wa; wv.y = wb; wv.z = wc; wv.w = wd;
                const bf16x8 pfz = __builtin_bit_cast(bf16x8, wv);
                oacc[0][n] = __builtin_amdgcn_mfma_f32_16x16x32_bf16(vc[0][z], pfz, oacc[0][n], 0, 0, 0);
                oacc[1][n] = __builtin_amdgcn_mfma_f32_16x16x32_bf16(vc[1][z], pfz, oacc[1][n], 0, 0, 0);
            }
        }
    }

    // ---- l reduce + 4-wave combine -> partial write ----
#pragma unroll
    for (int n = 0; n < NQ; ++n) {
        l_part[n] += __shfl_xor(l_part[n], 16);
        l_part[n] += __shfl_xor(l_part[n], 32);
    }
    if (lg == 0) {
#pragma unroll
        for (int n = 0; n < NQ; ++n)
            lbuf[w][n * 16 + lq] = l_part[n];
    }
    if (w >= 2) {
#pragma unroll
        for (int n = 0; n < NQ; ++n)
#pragma unroll
            for (int dt = 0; dt < 2; ++dt)
                *(f32x4*)&Ob[((size_t)(w - 2) * 128 + n * 16 + lq) * 36 + dt * 16 + lg * 4] = oacc[dt][n];
    }
    __syncthreads();
    if (w < 2) {
#pragma unroll
        for (int n = 0; n < NQ; ++n)
#pragma unroll
            for (int dt = 0; dt < 2; ++dt) {
                float* p = &Ob[((size_t)w * 128 + n * 16 + lq) * 36 + dt * 16 + lg * 4];
                f32x4 v = *(f32x4*)p;
                v += oacc[dt][n];
                *(f32x4*)p = v;
            }
    }
    __syncthreads();
    {
        const int pidx = (quarter * 32 + bh) * 4 + qt;
        const int q  = t >> 3;           // 0..31
        const int d0 = (t & 7) * 4;      // 0..28
#pragma unroll
        for (int rh = 0; rh < 4; ++rh) {
            const int row = q + rh * 32;
            f32x4 s0 = *(const f32x4*)&Ob[((size_t)row) * 36 + d0];
            f32x4 s1 = *(const f32x4*)&Ob[((size_t)(128 + row)) * 36 + d0];
            s0 += s1;
            *(f32x4*)(Opart + (size_t)pidx * 4096 + row * 32 + d0) = s0;
            if ((t & 7) == 0) {
                float gl = lbuf[0][row] + lbuf[1][row] + lbuf[2][row] + lbuf[3][row];
                lpart[(size_t)pidx * 128 + row] = gl;
            }
        }
    }
}

// ---------------------------------------------------------------------------
// Combine the 4 KV-quarter partials: Out = sum(Oq)/sum(lq). Grid 128 =
// bh*4+qt, 256 thr, 4 x float4 per thread.
// ---------------------------------------------------------------------------
__global__ __launch_bounds__(256) void attn_combine_kernel(
    const float* __restrict__ Opart, const float* __restrict__ lpart,
    float* __restrict__ Out)
{
    const int cb = blockIdx.x;               // 0..127
    const int bh = cb >> 2, qt = cb & 3;
    const int b = bh >> 3, h = bh & 7;
    const int t = threadIdx.x;
    const int q = t >> 3;                    // 0..31
    const int dq = (t & 7) * 4;              // 0..28
#pragma unroll
    for (int rh = 0; rh < 4; ++rh) {
        const int row = q + rh * 32;
        float4 o = {0.f, 0.f, 0.f, 0.f};
        float l = 0.f;
#pragma unroll
        for (int j = 0; j < 4; ++j) {
            const size_t pidx = (size_t)((j * 32 + bh) * 4 + qt);
            const float4 a = *(const float4*)(Opart + pidx * 4096 + row * 32 + dq);
            o.x += a.x; o.y += a.y; o.z += a.z; o.w += a.w;
            l += lpart[pidx * 128 + row];
        }
        const float inv = 1.0f / l;
        o.x *= inv; o.y *= inv; o.z *= inv; o.w *= inv;
        *(float4*)(Out + ((size_t)b * LQ + qt * 128 + row) * 256 + h * 32 + dq) = o;
    }
}

// ---------------------------------------------------------------------------
extern "C" void kernel_launch(void* const* d_in, const int* in_sizes, int n_in,
                              void* d_out, int out_size, void* d_ws, size_t ws_size,
                              hipStream_t stream)
{
    const float* hidden = (const float*)d_in[0];
    const float* inputs = (const float*)d_in[1];
    const float* ln1g   = (const float*)d_in[2];
    const float* ln1b   = (const float*)d_in[3];
    const float* ln2g   = (const float*)d_in[4];
    const float* ln2b   = (const float*)d_in[5];
    const float* Wq     = (const float*)d_in[6];
    const float* bq     = (const float*)d_in[7];
    const float* Wk     = (const float*)d_in[8];
    const float* bk     = (const float*)d_in[9];
    const float* Wv     = (const float*)d_in[10];
    const float* bv     = (const float*)d_in[11];
    float* out = (float*)d_out;

    // workspace (bytes), total ~66 MB
    char* wsb = (char*)d_ws;
    ushort* qb     = (ushort*)(wsb);                               // 1 MB   [32][512][32]
    ushort* WtKV   = (ushort*)(wsb + (1u << 20));                  // 0.5 MB [512][512]
    ushort* WtQ    = (ushort*)(wsb + (1u << 20) + (512u << 10));   // 0.5 MB [256][1024]
    float*  mean_h = (float*)(wsb + (2u << 20));                   // 8 KB
    float*  rstd_h = (float*)(wsb + (2u << 20) + 8192);            // 8 KB
    ushort* kb     = (ushort*)(wsb + (2u << 20) + 16384);          // 16 MB  [32][8192][32]
    ushort* vt     = (ushort*)(wsb + (18u << 20) + 16384);         // 16 MB  [32][32][8192]
    ushort* Abf    = (ushort*)(wsb + (34u << 20) + 16384);         // 32 MB  [32768][512]

    // Attention partials alias Abf (dead after phaseB): 8 MB + 256 KB << 32 MB
    float* Opart = (float*)Abf;                        // [4][32][4][128][32] f32
    float* lpart = Opart + (size_t)4 * 32 * 4 * 4096;  // [4][32][4][128] f32

    const float oscale = 0.2550540226496112f;   // log2(e)/sqrt(32): log2-domain softmax

    phaseA_kernel<<<8832, 256, 0, stream>>>(inputs, ln2g, ln2b, Abf,
                                            hidden, mean_h, rstd_h,
                                            Wq, Wk, Wv, WtQ, WtKV);
    phaseB_kernel<<<2176, 256, 0, stream>>>(Abf, WtKV, bk, bv, kb, vt,
                                            hidden, mean_h, rstd_h, ln1g, ln1b,
                                            WtQ, bq, qb, oscale);
    attn_mfma_kernel<<<512, 256, 0, stream>>>(qb, kb, vt, Opart, lpart);
    attn_combine_kernel<<<128, 256, 0, stream>>>(Opart, lpart, out);
}